// Round 5
// baseline (12690.385 us; speedup 1.0000x reference)
//
#include <hip/hip_runtime.h>
#include <hip/hip_bf16.h>
#include <cstdint>
#include <cstddef>
#include <math.h>

// ================= ALL-FP32 PROBE ROUND =================
// Purpose: distinguish precision-class error (bf16 noise flipping MoE top-2
// selection vs fp32 numpy ref) from logic-class error. No bf16 anywhere.

// ---------- RMSNorm (row=1024 fp32 -> fp32) ----------
__global__ __launch_bounds__(256) void rms32_k(const float* __restrict__ x,
                                               const float* __restrict__ w,
                                               float* __restrict__ o) {
  const int row = blockIdx.x, tid = threadIdx.x;
  const float* xr = x + (size_t)row * 1024;
  float4 v = *(const float4*)&xr[tid * 4];
  float ss = v.x * v.x + v.y * v.y + v.z * v.z + v.w * v.w;
#pragma unroll
  for (int off = 32; off; off >>= 1) ss += __shfl_down(ss, off);
  __shared__ float red[4];
  if ((tid & 63) == 0) red[tid >> 6] = ss;
  __syncthreads();
  float rs = rsqrtf((red[0] + red[1] + red[2] + red[3]) * (1.f / 1024.f) + 1e-5f);
  float4 wv = *(const float4*)&w[tid * 4];
  float4 ov;
  ov.x = v.x * rs * wv.x; ov.y = v.y * rs * wv.y;
  ov.z = v.z * rs * wv.z; ov.w = v.w * rs * wv.w;
  *(float4*)&o[(size_t)row * 1024 + tid * 4] = ov;
}

// ---------- fp32 tiled GEMM: C[M,N] = A[M,K] @ B[N,K]^T ----------
// 128x128 tile, BK=16, 256 threads, 8x8 per thread.
// EPI 0: store. 1: silu store. 2: +resid store. 4: C += resid[row*8]*val.
template <int EPI>
__global__ __launch_bounds__(256)
void gemm32_k(const float* __restrict__ A, const float* __restrict__ B,
              float* __restrict__ C, const float* __restrict__ resid,
              int M, int N, int K) {
  __shared__ float sA[16][128];
  __shared__ float sB[16][128];
  const int tid = threadIdx.x;
  const int bn = blockIdx.x, bm = blockIdx.y;
  const int tx = tid & 15, ty = tid >> 4;
  const int r4 = tid >> 2;        // 0..63
  const int c4 = (tid & 3) * 4;   // 0,4,8,12

  float acc[8][8];
#pragma unroll
  for (int i = 0; i < 8; i++)
#pragma unroll
    for (int j = 0; j < 8; j++) acc[i][j] = 0.f;

  for (int k0 = 0; k0 < K; k0 += 16) {
    __syncthreads();
#pragma unroll
    for (int jj = 0; jj < 2; jj++) {
      const int row = r4 + jj * 64;
      float4 a = *(const float4*)&A[(size_t)(bm * 128 + row) * K + k0 + c4];
      sA[c4 + 0][row] = a.x; sA[c4 + 1][row] = a.y;
      sA[c4 + 2][row] = a.z; sA[c4 + 3][row] = a.w;
      float4 b = *(const float4*)&B[(size_t)(bn * 128 + row) * K + k0 + c4];
      sB[c4 + 0][row] = b.x; sB[c4 + 1][row] = b.y;
      sB[c4 + 2][row] = b.z; sB[c4 + 3][row] = b.w;
    }
    __syncthreads();
#pragma unroll
    for (int k = 0; k < 16; k++) {
      float a8[8], b8[8];
      *(float4*)&a8[0] = *(const float4*)&sA[k][ty * 8];
      *(float4*)&a8[4] = *(const float4*)&sA[k][ty * 8 + 4];
      *(float4*)&b8[0] = *(const float4*)&sB[k][tx * 8];
      *(float4*)&b8[4] = *(const float4*)&sB[k][tx * 8 + 4];
#pragma unroll
      for (int i = 0; i < 8; i++)
#pragma unroll
        for (int j = 0; j < 8; j++) acc[i][j] += a8[i] * b8[j];
    }
  }

#pragma unroll
  for (int i = 0; i < 8; i++) {
    const int rg = bm * 128 + ty * 8 + i;
#pragma unroll
    for (int j = 0; j < 8; j++) {
      const int col = bn * 128 + tx * 8 + j;
      const size_t idx = (size_t)rg * N + col;
      float xv = acc[i][j];
      if (EPI == 0) {
        C[idx] = xv;
      } else if (EPI == 1) {
        C[idx] = xv / (1.f + __expf(-xv));
      } else if (EPI == 2) {
        C[idx] = xv + resid[idx];
      } else {
        C[idx] += resid[(size_t)rg * 8] * xv;
      }
    }
  }
}

// ---------- simple fp32 attention, 1 wave per (b,h,q) ----------
__global__ __launch_bounds__(64)
void attn32_k(const float* __restrict__ Q, int ldq,
              const float* __restrict__ K, int ldk,
              const float* __restrict__ V, int ldv,
              float* __restrict__ O, int ldo,
              int Tq, int Tkv, int causal, float scale) {
  __shared__ float sq[64];
  __shared__ float sS[1024];
  const int b = blockIdx.z, h = blockIdx.y, q = blockIdx.x;
  const int lane = threadIdx.x;
  const int hoff = h * 64;

  sq[lane] = Q[(size_t)(b * Tq + q) * ldq + hoff + lane];
  __syncthreads();

  const int nkv = causal ? (q + 1) : Tkv;
  float lmax = -1e30f;
  for (int kv = lane; kv < nkv; kv += 64) {
    const float* kr = &K[(size_t)(b * Tkv + kv) * ldk + hoff];
    float acc = 0.f;
#pragma unroll 8
    for (int d = 0; d < 64; d++) acc += kr[d] * sq[d];
    acc *= scale;
    sS[kv] = acc;
    lmax = fmaxf(lmax, acc);
  }
#pragma unroll
  for (int off = 32; off; off >>= 1) lmax = fmaxf(lmax, __shfl_xor(lmax, off));
  __syncthreads();
  float lsum = 0.f;
  for (int kv = lane; kv < nkv; kv += 64) {
    float e = __expf(sS[kv] - lmax);
    sS[kv] = e;
    lsum += e;
  }
#pragma unroll
  for (int off = 32; off; off >>= 1) lsum += __shfl_xor(lsum, off);
  __syncthreads();
  const float inv = 1.f / lsum;
  float o = 0.f;
  for (int kv = 0; kv < nkv; kv++)
    o += sS[kv] * V[(size_t)(b * Tkv + kv) * ldv + hoff + lane];
  O[(size_t)(b * Tq + q) * ldo + hoff + lane] = o * inv;
}

// ---------- MoE gating in FP64 -> per-token dense gate row [N][8] ----------
__global__ __launch_bounds__(256) void gate_k(const float* __restrict__ H,
                                              const float* __restrict__ w3,
                                              const float* __restrict__ gw,
                                              float* __restrict__ gates) {
  const int token = blockIdx.x * 4 + (threadIdx.x >> 6);
  const int lane = threadIdx.x & 63;
  const float* xr = H + (size_t)token * 1024;
  double a[8] = {0, 0, 0, 0, 0, 0, 0, 0};
  double ss = 0.0;
#pragma unroll
  for (int i = 0; i < 4; i++) {
    float4 xv = *(const float4*)&xr[i * 256 + lane * 4];
    float4 w3v = *(const float4*)&w3[i * 256 + lane * 4];
    ss += (double)xv.x * xv.x + (double)xv.y * xv.y + (double)xv.z * xv.z + (double)xv.w * xv.w;
    double xw0 = (double)xv.x * (double)w3v.x, xw1 = (double)xv.y * (double)w3v.y;
    double xw2 = (double)xv.z * (double)w3v.z, xw3 = (double)xv.w * (double)w3v.w;
#pragma unroll
    for (int e = 0; e < 8; e++) {
      float4 wv = *(const float4*)&gw[e * 1024 + i * 256 + lane * 4];
      a[e] += xw0 * wv.x + xw1 * wv.y + xw2 * wv.z + xw3 * wv.w;
    }
  }
#pragma unroll
  for (int off = 32; off; off >>= 1) {
    ss += __shfl_down(ss, off);
#pragma unroll
    for (int e = 0; e < 8; e++) a[e] += __shfl_down(a[e], off);
  }
  if (lane == 0) {
    double v0 = a[0]; int i0 = 0;
#pragma unroll
    for (int e = 1; e < 8; e++) if (a[e] > v0) { v0 = a[e]; i0 = e; }
    double v1 = -1e300; int i1 = 0;
#pragma unroll
    for (int e = 0; e < 8; e++) if (e != i0 && a[e] > v1) { v1 = a[e]; i1 = e; }
    double rs = 1.0 / sqrt(ss * (1.0 / 1024.0) + 1e-5);
    double t = exp((v1 - v0) * rs);
    double g0 = 1.0 / (1.0 + t);
    float gr[8] = {0.f, 0.f, 0.f, 0.f, 0.f, 0.f, 0.f, 0.f};
    gr[i0] = (float)g0;
    gr[i1] = (float)(1.0 - g0);
#pragma unroll
    for (int e = 0; e < 8; e++) gates[(size_t)token * 8 + e] = gr[e];
  }
}

// ---------- final: out = H + moe_acc ----------
__global__ __launch_bounds__(256) void add_k(const float* __restrict__ H,
                                             const float* __restrict__ acc,
                                             float* __restrict__ out) {
  const size_t i = ((size_t)blockIdx.x * 256 + threadIdx.x) * 4;
  float4 hv = *(const float4*)&H[i];
  float4 av = *(const float4*)&acc[i];
  float4 ov;
  ov.x = hv.x + av.x; ov.y = hv.y + av.y; ov.z = hv.z + av.z; ov.w = hv.w + av.w;
  *(float4*)&out[i] = ov;
}

// ---------- host ----------
extern "C" void kernel_launch(void* const* d_in, const int* in_sizes, int n_in,
                              void* d_out, int out_size, void* d_ws, size_t ws_size,
                              hipStream_t stream) {
  (void)in_sizes; (void)n_in; (void)out_size;
  const float* x     = (const float*)d_in[0];
  const float* enc   = (const float*)d_in[1];
  const float* n1w   = (const float*)d_in[4];
  const float* n2w   = (const float*)d_in[5];
  const float* n3w   = (const float*)d_in[6];
  const float* sa_wq = (const float*)d_in[7];
  const float* sa_wk = (const float*)d_in[8];
  const float* sa_wv = (const float*)d_in[9];
  const float* sa_wo = (const float*)d_in[10];
  const float* ca_wq = (const float*)d_in[11];
  const float* ca_wk = (const float*)d_in[12];
  const float* ca_wv = (const float*)d_in[13];
  const float* ca_wo = (const float*)d_in[14];
  const float* gw    = (const float*)d_in[15];
  const float* e_w1  = (const float*)d_in[16];
  const float* e_w2  = (const float*)d_in[17];
  const float* s_w1  = (const float*)d_in[18];
  const float* s_w2  = (const float*)d_in[19];
  float* out = (float*)d_out;

  char* p = (char*)d_ws;
  size_t off = 0;
  auto alloc = [&](size_t bytes) -> float* {
    void* r = p + off;
    off += (bytes + 255) & ~(size_t)255;
    return (float*)r;
  };
  float* xnf    = alloc(4096LL * 1024 * 4);
  float* Qb     = alloc(4096LL * 1024 * 4);
  float* Kb     = alloc(4096LL * 1024 * 4);
  float* Vb     = alloc(4096LL * 1024 * 4);
  float* att    = alloc(4096LL * 1024 * 4);
  float* Hb     = alloc(4096LL * 1024 * 4);
  float* hid    = alloc(4096LL * 4096 * 4);
  float* moeacc = alloc(4096LL * 1024 * 4);
  float* gates  = alloc(4096LL * 8 * 4);
  if (off > ws_size) return;

  // ---- self attention ----
  rms32_k<<<4096, 256, 0, stream>>>(x, n1w, xnf);
  gemm32_k<0><<<dim3(8, 32), 256, 0, stream>>>(xnf, sa_wq, Qb, nullptr, 4096, 1024, 1024);
  gemm32_k<0><<<dim3(8, 32), 256, 0, stream>>>(xnf, sa_wk, Kb, nullptr, 4096, 1024, 1024);
  gemm32_k<0><<<dim3(8, 32), 256, 0, stream>>>(xnf, sa_wv, Vb, nullptr, 4096, 1024, 1024);
  attn32_k<<<dim3(1024, 16, 4), 64, 0, stream>>>(Qb, 1024, Kb, 1024, Vb, 1024,
      att, 1024, 1024, 1024, 1, 0.125f);
  gemm32_k<2><<<dim3(8, 32), 256, 0, stream>>>(att, sa_wo, Hb, x, 4096, 1024, 1024);

  // ---- cross attention ----
  rms32_k<<<4096, 256, 0, stream>>>(Hb, n2w, xnf);
  gemm32_k<0><<<dim3(8, 32), 256, 0, stream>>>(xnf, ca_wq, Qb, nullptr, 4096, 1024, 1024);
  gemm32_k<0><<<dim3(8, 2), 256, 0, stream>>>(enc, ca_wk, Kb, nullptr, 256, 1024, 1024);
  gemm32_k<0><<<dim3(8, 2), 256, 0, stream>>>(enc, ca_wv, Vb, nullptr, 256, 1024, 1024);
  attn32_k<<<dim3(1024, 16, 4), 64, 0, stream>>>(Qb, 1024, Kb, 1024, Vb, 1024,
      att, 1024, 1024, 64, 0, 0.125f);
  gemm32_k<2><<<dim3(8, 32), 256, 0, stream>>>(att, ca_wo, Hb, Hb, 4096, 1024, 1024);

  // ---- MoE (dense experts, fp64 gating, all fp32) ----
  rms32_k<<<4096, 256, 0, stream>>>(Hb, n3w, xnf);
  gate_k<<<1024, 256, 0, stream>>>(Hb, n3w, gw, gates);
  // shared expert
  gemm32_k<1><<<dim3(32, 32), 256, 0, stream>>>(xnf, s_w1, hid, nullptr, 4096, 4096, 1024);
  gemm32_k<0><<<dim3(8, 32), 256, 0, stream>>>(hid, s_w2, moeacc, nullptr, 4096, 1024, 4096);
  // experts: dense, gate-weighted accumulate
  for (int e = 0; e < 8; e++) {
    gemm32_k<1><<<dim3(32, 32), 256, 0, stream>>>(xnf, e_w1 + (size_t)e * 4096 * 1024,
        hid, nullptr, 4096, 4096, 1024);
    gemm32_k<4><<<dim3(8, 32), 256, 0, stream>>>(hid, e_w2 + (size_t)e * 1024 * 4096,
        moeacc, gates + e, 4096, 1024, 4096);
  }

  add_k<<<4096, 256, 0, stream>>>(Hb, moeacc, out);
}

// Round 6
// 2759.057 us; speedup vs baseline: 4.5995x; 4.5995x over previous
//
#include <hip/hip_runtime.h>
#include <hip/hip_bf16.h>
#include <cstdint>
#include <cstddef>
#include <math.h>

// ---------- types ----------
typedef __attribute__((ext_vector_type(8))) short bf16x8;
typedef __attribute__((ext_vector_type(4))) float f32x4;
typedef __attribute__((ext_vector_type(4))) short s16x4;

static __device__ __forceinline__ short f2bf(float f) {
  union { __hip_bfloat16 b; short s; } u;
  u.b = __float2bfloat16(f);
  return u.s;
}

static __device__ __forceinline__ void gload_lds16(const short* g, short* l) {
  __builtin_amdgcn_global_load_lds((const __attribute__((address_space(1))) void*)g,
                                   (__attribute__((address_space(3))) void*)l,
                                   16, 0, 0);
}

// ---------- fp32 -> bf16 convert ----------
__global__ __launch_bounds__(256) void cvt_k(const float* __restrict__ src,
                                             short* __restrict__ dst, long n4) {
  long i = (long)blockIdx.x * blockDim.x + threadIdx.x;
  long stride = (long)gridDim.x * blockDim.x;
  for (; i < n4; i += stride) {
    float4 v = ((const float4*)src)[i];
    s16x4 o;
    o.x = f2bf(v.x); o.y = f2bf(v.y); o.z = f2bf(v.z); o.w = f2bf(v.w);
    ((s16x4*)dst)[i] = o;
  }
}

// ---------- RMSNorm fp32 -> fp32 ----------
__global__ __launch_bounds__(256) void rms32_k(const float* __restrict__ x,
                                               const float* __restrict__ w,
                                               float* __restrict__ o) {
  const int row = blockIdx.x, tid = threadIdx.x;
  const float* xr = x + (size_t)row * 1024;
  float4 v = *(const float4*)&xr[tid * 4];
  float ss = v.x * v.x + v.y * v.y + v.z * v.z + v.w * v.w;
#pragma unroll
  for (int off = 32; off; off >>= 1) ss += __shfl_down(ss, off);
  __shared__ float red[4];
  if ((tid & 63) == 0) red[tid >> 6] = ss;
  __syncthreads();
  float rs = rsqrtf((red[0] + red[1] + red[2] + red[3]) * (1.f / 1024.f) + 1e-5f);
  float4 wv = *(const float4*)&w[tid * 4];
  float4 ov;
  ov.x = v.x * rs * wv.x; ov.y = v.y * rs * wv.y;
  ov.z = v.z * rs * wv.z; ov.w = v.w * rs * wv.w;
  *(float4*)&o[(size_t)row * 1024 + tid * 4] = ov;
}

// ---------- RMSNorm fp32 -> bf16 (for MoE expert inputs) ----------
__global__ __launch_bounds__(256) void rms_k(const float* __restrict__ x,
                                             const float* __restrict__ w,
                                             short* __restrict__ obf) {
  const int row = blockIdx.x, tid = threadIdx.x;
  const float* xr = x + (size_t)row * 1024;
  float4 v = *(const float4*)&xr[tid * 4];
  float ss = v.x * v.x + v.y * v.y + v.z * v.z + v.w * v.w;
#pragma unroll
  for (int off = 32; off; off >>= 1) ss += __shfl_down(ss, off);
  __shared__ float red[4];
  if ((tid & 63) == 0) red[tid >> 6] = ss;
  __syncthreads();
  float rs = rsqrtf((red[0] + red[1] + red[2] + red[3]) * (1.f / 1024.f) + 1e-5f);
  float4 wv = *(const float4*)&w[tid * 4];
  s16x4 ob;
  ob.x = f2bf(v.x * rs * wv.x); ob.y = f2bf(v.y * rs * wv.y);
  ob.z = f2bf(v.z * rs * wv.z); ob.w = f2bf(v.w * rs * wv.w);
  *(s16x4*)&obf[(size_t)row * 1024 + tid * 4] = ob;
}

// ---------- fp32 tiled GEMM: C[M,N] = A[M,K] @ B[N,K]^T (PROVEN r5) ----------
// EPI 0: store. 2: +resid store.
template <int EPI>
__global__ __launch_bounds__(256)
void gemm32_k(const float* __restrict__ A, const float* __restrict__ B,
              float* __restrict__ C, const float* __restrict__ resid,
              int M, int N, int K) {
  __shared__ float sA[16][128];
  __shared__ float sB[16][128];
  const int tid = threadIdx.x;
  const int bn = blockIdx.x, bm = blockIdx.y;
  const int tx = tid & 15, ty = tid >> 4;
  const int r4 = tid >> 2;
  const int c4 = (tid & 3) * 4;

  float acc[8][8];
#pragma unroll
  for (int i = 0; i < 8; i++)
#pragma unroll
    for (int j = 0; j < 8; j++) acc[i][j] = 0.f;

  for (int k0 = 0; k0 < K; k0 += 16) {
    __syncthreads();
#pragma unroll
    for (int jj = 0; jj < 2; jj++) {
      const int row = r4 + jj * 64;
      float4 a = *(const float4*)&A[(size_t)(bm * 128 + row) * K + k0 + c4];
      sA[c4 + 0][row] = a.x; sA[c4 + 1][row] = a.y;
      sA[c4 + 2][row] = a.z; sA[c4 + 3][row] = a.w;
      float4 b = *(const float4*)&B[(size_t)(bn * 128 + row) * K + k0 + c4];
      sB[c4 + 0][row] = b.x; sB[c4 + 1][row] = b.y;
      sB[c4 + 2][row] = b.z; sB[c4 + 3][row] = b.w;
    }
    __syncthreads();
#pragma unroll
    for (int k = 0; k < 16; k++) {
      float a8[8], b8[8];
      *(float4*)&a8[0] = *(const float4*)&sA[k][ty * 8];
      *(float4*)&a8[4] = *(const float4*)&sA[k][ty * 8 + 4];
      *(float4*)&b8[0] = *(const float4*)&sB[k][tx * 8];
      *(float4*)&b8[4] = *(const float4*)&sB[k][tx * 8 + 4];
#pragma unroll
      for (int i = 0; i < 8; i++)
#pragma unroll
        for (int j = 0; j < 8; j++) acc[i][j] += a8[i] * b8[j];
    }
  }

#pragma unroll
  for (int i = 0; i < 8; i++) {
    const int rg = bm * 128 + ty * 8 + i;
#pragma unroll
    for (int j = 0; j < 8; j++) {
      const int col = bn * 128 + tx * 8 + j;
      const size_t idx = (size_t)rg * N + col;
      float xv = acc[i][j];
      if (EPI == 0) C[idx] = xv;
      else C[idx] = xv + resid[idx];
    }
  }
}

// ---------- fp32 tiled flash attention: 4 waves, 64 q-rows/block ----------
// wave wv owns q rows wv*16+lr; lane (lr,lg): scores kv=lg*16+j, output dims d=lg*16+j.
__global__ __launch_bounds__(256)
void attn32f_k(const float* __restrict__ Q, int ldq,
               const float* __restrict__ K, int ldk,
               const float* __restrict__ V, int ldv,
               float* __restrict__ O, int ldo,
               int Tq, int Tkv, int causal, float scale) {
  __shared__ float sK[64][64];
  __shared__ float sV[64][64];
  __shared__ float sP[4][16][68];  // pad 68: kv reads spread over 8 banks

  const int qb = blockIdx.x, h = blockIdx.y, b = blockIdx.z;
  const int tid = threadIdx.x, lane = tid & 63, wv = tid >> 6;
  const int lr = lane & 15, lg = lane >> 4;
  const int hoff = h * 64;
  const int qrow = qb * 64 + wv * 16 + lr;

  float q[64];
  {
    const float* qp = &Q[(size_t)(b * Tq + qrow) * ldq + hoff];
#pragma unroll
    for (int d4 = 0; d4 < 16; d4++) *(float4*)&q[d4 * 4] = *(const float4*)&qp[d4 * 4];
  }

  float m_run = -1e30f, l_run = 0.f;
  float o[16];
#pragma unroll
  for (int j = 0; j < 16; j++) o[j] = 0.f;

  const int ntiles = causal ? (qb + 1) : (Tkv >> 6);
  for (int kt = 0; kt < ntiles; ++kt) {
    __syncthreads();
    {
      const int row = tid >> 2, c0 = (tid & 3) * 16;
      const float* kp = &K[(size_t)(b * Tkv + kt * 64 + row) * ldk + hoff + c0];
      const float* vp = &V[(size_t)(b * Tkv + kt * 64 + row) * ldv + hoff + c0];
#pragma unroll
      for (int j4 = 0; j4 < 4; j4++) {
        *(float4*)&sK[row][c0 + j4 * 4] = *(const float4*)&kp[j4 * 4];
        *(float4*)&sV[row][c0 + j4 * 4] = *(const float4*)&vp[j4 * 4];
      }
    }
    __syncthreads();

    float s[16];
    float tmax = -1e30f;
#pragma unroll
    for (int j = 0; j < 16; j++) {
      const int kvl = lg * 16 + j;
      float acc = 0.f;
#pragma unroll
      for (int d = 0; d < 64; d++) acc += q[d] * sK[kvl][d];
      acc *= scale;
      if (causal && (kt * 64 + kvl) > qrow) acc = -1e30f;
      s[j] = acc;
      tmax = fmaxf(tmax, acc);
    }
    tmax = fmaxf(tmax, __shfl_xor(tmax, 16));
    tmax = fmaxf(tmax, __shfl_xor(tmax, 32));
    const float m_new = fmaxf(m_run, tmax);
    const float alpha = __expf(m_run - m_new);
    float tsum = 0.f;
#pragma unroll
    for (int j = 0; j < 16; j++) {
      float e = (s[j] <= -1e29f) ? 0.f : __expf(s[j] - m_new);
      s[j] = e; tsum += e;
    }
    tsum += __shfl_xor(tsum, 16);
    tsum += __shfl_xor(tsum, 32);
    l_run = l_run * alpha + tsum;
    m_run = m_new;

#pragma unroll
    for (int j = 0; j < 16; j++) sP[wv][lr][lg * 16 + j] = s[j];
#pragma unroll
    for (int j = 0; j < 16; j++) o[j] *= alpha;
    __syncthreads();  // order P writes (and protect sV before next stage)

#pragma unroll 4
    for (int kv = 0; kv < 64; kv++) {
      const float pv = sP[wv][lr][kv];
      const float* vr = &sV[kv][lg * 16];
#pragma unroll
      for (int j = 0; j < 16; j++) o[j] += pv * vr[j];
    }
  }

  const float inv = 1.f / l_run;
  float* op = &O[(size_t)(b * Tq + qrow) * ldo + hoff + lg * 16];
#pragma unroll
  for (int j4 = 0; j4 < 4; j4++) {
    float4 ov;
    ov.x = o[j4 * 4 + 0] * inv; ov.y = o[j4 * 4 + 1] * inv;
    ov.z = o[j4 * 4 + 2] * inv; ov.w = o[j4 * 4 + 3] * inv;
    *(float4*)&op[j4 * 4] = ov;
  }
}

// ---------- bf16 MFMA GEMM: C[M,N] = A[M,K] @ B[N,K]^T ----------
// MODE 0: dense. MODE 1: A rows gathered via row_map. MODE 2: A rows contiguous from offs[e].
// EPI 1: silu->bf16. EPI 3: fp32 store.
template <int EPI, int MODE>
__global__ __launch_bounds__(256)
void gemm_bt_k(const short* __restrict__ A, const short* __restrict__ B,
               void* C, int M, int N, int K,
               const int* __restrict__ row_map,
               const int* __restrict__ counts,
               const int* __restrict__ offs) {
  __shared__ short sA[128 * 32];
  __shared__ short sB[128 * 32];
  __shared__ int sRow[128];

  const int tid = threadIdx.x;
  const int bn = blockIdx.x, bm = blockIdx.y;
  int base = 0, cnt = M;
  const short* Bp = B;
  if (MODE != 0) {
    const int e = blockIdx.z;
    cnt = counts[e];
    base = offs[e];
    if (bm * 128 >= cnt) return;
    Bp += (size_t)e * N * K;
  }
  const int lane = tid & 63, wv = tid >> 6;
  const int rch = lane >> 2, cch = (lane & 3) << 3;
  const int wr = wv >> 1, wc = wv & 1;
  const int lr = lane & 15, lg = lane >> 4;
  const int c0 = wv * 2, c1 = wv * 2 + 1;

  int ra0 = 0, ra1 = 0;
  if (MODE == 0) {
    ra0 = bm * 128 + c0 * 16 + rch;
    ra1 = bm * 128 + c1 * 16 + rch;
  } else if (MODE == 2) {
    int rl0 = bm * 128 + c0 * 16 + rch, rl1 = bm * 128 + c1 * 16 + rch;
    ra0 = base + ((rl0 < cnt) ? rl0 : 0);
    ra1 = base + ((rl1 < cnt) ? rl1 : 0);
  } else {
    if (tid < 128) {
      int r = bm * 128 + tid;
      sRow[tid] = (r < cnt) ? row_map[base + r] : row_map[base];
    }
    __syncthreads();
    ra0 = sRow[c0 * 16 + rch];
    ra1 = sRow[c1 * 16 + rch];
  }
  const int rb0 = bn * 128 + c0 * 16 + rch, rb1 = bn * 128 + c1 * 16 + rch;

  f32x4 acc[4][4];
#pragma unroll
  for (int m = 0; m < 4; m++)
#pragma unroll
    for (int n = 0; n < 4; n++) acc[m][n] = (f32x4){0.f, 0.f, 0.f, 0.f};

  const int nk = K >> 5;
  for (int kt = 0; kt < nk; ++kt) {
    __syncthreads();
    const int colk = (kt << 5) + cch;
    gload_lds16(A + (size_t)ra0 * K + colk, &sA[c0 * 512]);
    gload_lds16(A + (size_t)ra1 * K + colk, &sA[c1 * 512]);
    gload_lds16(Bp + (size_t)rb0 * K + colk, &sB[c0 * 512]);
    gload_lds16(Bp + (size_t)rb1 * K + colk, &sB[c1 * 512]);
    __syncthreads();
    bf16x8 a[4], b[4];
#pragma unroll
    for (int m = 0; m < 4; m++) a[m] = *(const bf16x8*)&sA[(wr * 64 + m * 16 + lr) * 32 + lg * 8];
#pragma unroll
    for (int n = 0; n < 4; n++) b[n] = *(const bf16x8*)&sB[(wc * 64 + n * 16 + lr) * 32 + lg * 8];
#pragma unroll
    for (int m = 0; m < 4; m++)
#pragma unroll
      for (int n = 0; n < 4; n++)
        acc[m][n] = __builtin_amdgcn_mfma_f32_16x16x32_bf16(a[m], b[n], acc[m][n], 0, 0, 0);
  }

  const int cbase = bn * 128 + wc * 64;
#pragma unroll
  for (int m = 0; m < 4; m++) {
    const int rl = wr * 64 + m * 16 + lg * 4;
#pragma unroll
    for (int n = 0; n < 4; n++) {
      f32x4 v = acc[m][n];
      const int col = cbase + n * 16 + lr;
#pragma unroll
      for (int j = 0; j < 4; j++) {
        const int rloc = bm * 128 + rl + j;
        if (MODE != 0 && rloc >= cnt) continue;
        const size_t rg = (MODE == 0) ? (size_t)rloc : (size_t)(base + rloc);
        const size_t idx = rg * (size_t)N + col;
        float xv = v[j];
        if (EPI == 1) {
          float s = xv / (1.f + __expf(-xv));
          ((short*)C)[idx] = f2bf(s);
        } else {
          ((float*)C)[idx] = xv;
        }
      }
    }
  }
}

// ---------- MoE gating FP64 (from fp32 H): top-2, slots ----------
__global__ __launch_bounds__(256) void gate_k(const float* __restrict__ H,
                                              const float* __restrict__ w3,
                                              const float* __restrict__ gw,
                                              int* counts, int* tok_e, int* tok_s,
                                              float* tok_g) {
  const int token = blockIdx.x * 4 + (threadIdx.x >> 6);
  const int lane = threadIdx.x & 63;
  const float* xr = H + (size_t)token * 1024;
  double a[8] = {0, 0, 0, 0, 0, 0, 0, 0};
  double ss = 0.0;
#pragma unroll
  for (int i = 0; i < 4; i++) {
    float4 xv = *(const float4*)&xr[i * 256 + lane * 4];
    float4 w3v = *(const float4*)&w3[i * 256 + lane * 4];
    ss += (double)xv.x * xv.x + (double)xv.y * xv.y + (double)xv.z * xv.z + (double)xv.w * xv.w;
    double xw0 = (double)xv.x * (double)w3v.x, xw1 = (double)xv.y * (double)w3v.y;
    double xw2 = (double)xv.z * (double)w3v.z, xw3 = (double)xv.w * (double)w3v.w;
#pragma unroll
    for (int e = 0; e < 8; e++) {
      float4 wv = *(const float4*)&gw[e * 1024 + i * 256 + lane * 4];
      a[e] += xw0 * wv.x + xw1 * wv.y + xw2 * wv.z + xw3 * wv.w;
    }
  }
#pragma unroll
  for (int off = 32; off; off >>= 1) {
    ss += __shfl_down(ss, off);
#pragma unroll
    for (int e = 0; e < 8; e++) a[e] += __shfl_down(a[e], off);
  }
  if (lane == 0) {
    double v0 = a[0]; int i0 = 0;
#pragma unroll
    for (int e = 1; e < 8; e++) if (a[e] > v0) { v0 = a[e]; i0 = e; }
    double v1 = -1e300; int i1 = 0;
#pragma unroll
    for (int e = 0; e < 8; e++) if (e != i0 && a[e] > v1) { v1 = a[e]; i1 = e; }
    double rs = 1.0 / sqrt(ss * (1.0 / 1024.0) + 1e-5);
    double t = exp((v1 - v0) * rs);
    double g0 = 1.0 / (1.0 + t);
    int s0 = atomicAdd(&counts[i0], 1);
    int s1 = atomicAdd(&counts[i1], 1);
    tok_e[2 * token] = i0; tok_e[2 * token + 1] = i1;
    tok_s[2 * token] = s0; tok_s[2 * token + 1] = s1;
    tok_g[2 * token] = (float)g0; tok_g[2 * token + 1] = (float)(1.0 - g0);
  }
}

__global__ void offsets_k(const int* counts, int* offs) {
  if (threadIdx.x == 0 && blockIdx.x == 0) {
    int s = 0;
    for (int e = 0; e < 8; e++) { offs[e] = s; s += counts[e]; }
  }
}

__global__ __launch_bounds__(256) void build_rows_k(const int* __restrict__ offs,
                                                    const int* __restrict__ tok_e,
                                                    const int* __restrict__ tok_s,
                                                    int* __restrict__ row_map,
                                                    int* __restrict__ tok_row) {
  int n = blockIdx.x * 256 + threadIdx.x;
  int e0 = tok_e[2 * n], e1 = tok_e[2 * n + 1];
  int r0 = offs[e0] + tok_s[2 * n], r1 = offs[e1] + tok_s[2 * n + 1];
  row_map[r0] = n; row_map[r1] = n;
  tok_row[2 * n] = r0; tok_row[2 * n + 1] = r1;
}

// ---------- final combine: out = H + shared + g0*eo0 + g1*eo1 ----------
__global__ __launch_bounds__(256) void combine_k(const float* __restrict__ H,
                                                 const float* __restrict__ sh,
                                                 const float* __restrict__ eo,
                                                 const int* __restrict__ tok_row,
                                                 const float* __restrict__ tok_g,
                                                 float* __restrict__ out) {
  const int n = blockIdx.x, t = threadIdx.x;
  const int r0 = tok_row[2 * n], r1 = tok_row[2 * n + 1];
  const float g0 = tok_g[2 * n], g1 = tok_g[2 * n + 1];
  const size_t ib = (size_t)n * 1024 + t * 4;
  float4 hv = *(const float4*)&H[ib];
  float4 sv = *(const float4*)&sh[ib];
  float4 a0 = *(const float4*)&eo[(size_t)r0 * 1024 + t * 4];
  float4 a1 = *(const float4*)&eo[(size_t)r1 * 1024 + t * 4];
  float4 ov;
  ov.x = hv.x + sv.x + g0 * a0.x + g1 * a1.x;
  ov.y = hv.y + sv.y + g0 * a0.y + g1 * a1.y;
  ov.z = hv.z + sv.z + g0 * a0.z + g1 * a1.z;
  ov.w = hv.w + sv.w + g0 * a0.w + g1 * a1.w;
  *(float4*)&out[ib] = ov;
}

// ---------- host ----------
extern "C" void kernel_launch(void* const* d_in, const int* in_sizes, int n_in,
                              void* d_out, int out_size, void* d_ws, size_t ws_size,
                              hipStream_t stream) {
  (void)in_sizes; (void)n_in; (void)out_size;
  const float* x     = (const float*)d_in[0];
  const float* enc   = (const float*)d_in[1];
  const float* n1w   = (const float*)d_in[4];
  const float* n2w   = (const float*)d_in[5];
  const float* n3w   = (const float*)d_in[6];
  const float* sa_wq = (const float*)d_in[7];
  const float* sa_wk = (const float*)d_in[8];
  const float* sa_wv = (const float*)d_in[9];
  const float* sa_wo = (const float*)d_in[10];
  const float* ca_wq = (const float*)d_in[11];
  const float* ca_wk = (const float*)d_in[12];
  const float* ca_wv = (const float*)d_in[13];
  const float* ca_wo = (const float*)d_in[14];
  const float* gw    = (const float*)d_in[15];
  const float* e_w1  = (const float*)d_in[16];
  const float* e_w2  = (const float*)d_in[17];
  const float* s_w1  = (const float*)d_in[18];
  const float* s_w2  = (const float*)d_in[19];
  float* out = (float*)d_out;

  char* p = (char*)d_ws;
  size_t off = 0;
  auto alloc = [&](size_t bytes) -> void* {
    void* r = p + off;
    off += (bytes + 255) & ~(size_t)255;
    return r;
  };
  short* w_sh1  = (short*)alloc(4096LL * 1024 * 2);
  short* w_sh2  = (short*)alloc(1024LL * 4096 * 2);
  short* w_e1   = (short*)alloc(8LL * 4096 * 1024 * 2);
  short* w_e2   = (short*)alloc(8LL * 1024 * 4096 * 2);
  short* xn     = (short*)alloc(4096LL * 1024 * 2);
  short* bufA   = (short*)alloc(4096LL * 4096 * 2);   // shared-expert hidden
  short* hbuf   = (short*)alloc(8192LL * 4096 * 2);   // routed hidden
  float* xnf    = (float*)alloc(4096LL * 1024 * 4);
  float* Qb     = (float*)alloc(4096LL * 1024 * 4);
  float* Kb     = (float*)alloc(4096LL * 1024 * 4);
  float* Vb     = (float*)alloc(4096LL * 1024 * 4);
  float* att    = (float*)alloc(4096LL * 1024 * 4);
  float* Hb     = (float*)alloc(4096LL * 1024 * 4);
  float* eo     = (float*)alloc(8192LL * 1024 * 4);
  float* shout  = (float*)alloc(4096LL * 1024 * 4);
  int*   counts = (int*)alloc(8 * 4);
  int*   offs   = (int*)alloc(8 * 4);
  int*   tok_e  = (int*)alloc(4096LL * 2 * 4);
  int*   tok_s  = (int*)alloc(4096LL * 2 * 4);
  float* tok_g  = (float*)alloc(4096LL * 2 * 4);
  int*   tok_row= (int*)alloc(4096LL * 2 * 4);
  int*   row_map= (int*)alloc(8192LL * 4);
  if (off > ws_size) return;

  auto cvt = [&](const float* s, short* d, long n) {
    long n4 = n / 4;
    long g = (n4 + 255) / 256;
    int grid = (int)(g > 4096 ? 4096 : g);
    cvt_k<<<grid, 256, 0, stream>>>(s, d, n4);
  };

  // MoE weights -> bf16
  cvt(s_w1, w_sh1, 4096L * 1024);
  cvt(s_w2, w_sh2, 4096L * 1024);
  cvt(e_w1, w_e1, 8L * 4096 * 1024);
  cvt(e_w2, w_e2, 8L * 1024 * 4096);

  // ---- self attention (all fp32: H must stay accurate for gating) ----
  rms32_k<<<4096, 256, 0, stream>>>(x, n1w, xnf);
  gemm32_k<0><<<dim3(8, 32), 256, 0, stream>>>(xnf, sa_wq, Qb, nullptr, 4096, 1024, 1024);
  gemm32_k<0><<<dim3(8, 32), 256, 0, stream>>>(xnf, sa_wk, Kb, nullptr, 4096, 1024, 1024);
  gemm32_k<0><<<dim3(8, 32), 256, 0, stream>>>(xnf, sa_wv, Vb, nullptr, 4096, 1024, 1024);
  attn32f_k<<<dim3(16, 16, 4), 256, 0, stream>>>(Qb, 1024, Kb, 1024, Vb, 1024,
      att, 1024, 1024, 1024, 1, 0.125f);
  gemm32_k<2><<<dim3(8, 32), 256, 0, stream>>>(att, sa_wo, Hb, x, 4096, 1024, 1024);

  // ---- cross attention (fp32) ----
  rms32_k<<<4096, 256, 0, stream>>>(Hb, n2w, xnf);
  gemm32_k<0><<<dim3(8, 32), 256, 0, stream>>>(xnf, ca_wq, Qb, nullptr, 4096, 1024, 1024);
  gemm32_k<0><<<dim3(8, 2), 256, 0, stream>>>(enc, ca_wk, Kb, nullptr, 256, 1024, 1024);
  gemm32_k<0><<<dim3(8, 2), 256, 0, stream>>>(enc, ca_wv, Vb, nullptr, 256, 1024, 1024);
  attn32f_k<<<dim3(16, 16, 4), 256, 0, stream>>>(Qb, 1024, Kb, 1024, Vb, 1024,
      att, 1024, 1024, 64, 0, 0.125f);
  gemm32_k<2><<<dim3(8, 32), 256, 0, stream>>>(att, ca_wo, Hb, Hb, 4096, 1024, 1024);

  // ---- MoE: fp64 gate from fp32 H; bf16 MFMA experts (routed top-2) ----
  rms_k<<<4096, 256, 0, stream>>>(Hb, n3w, xn);
  hipMemsetAsync(counts, 0, 8 * sizeof(int), stream);
  gate_k<<<1024, 256, 0, stream>>>(Hb, n3w, gw, counts, tok_e, tok_s, tok_g);
  offsets_k<<<1, 1, 0, stream>>>(counts, offs);
  build_rows_k<<<16, 256, 0, stream>>>(offs, tok_e, tok_s, row_map, tok_row);
  // expert w1 (gathered rows) + silu -> hbuf (bf16)
  gemm_bt_k<1, 1><<<dim3(32, 32, 8), 256, 0, stream>>>(xn, w_e1, hbuf,
      4096, 4096, 1024, row_map, counts, offs);
  // expert w2 (contiguous rows) -> eo (fp32)
  gemm_bt_k<3, 2><<<dim3(8, 32, 8), 256, 0, stream>>>(hbuf, w_e2, eo,
      4096, 1024, 4096, nullptr, counts, offs);
  // shared expert (dense bf16)
  gemm_bt_k<1, 0><<<dim3(32, 32), 256, 0, stream>>>(xn, w_sh1, bufA,
      4096, 4096, 1024, nullptr, nullptr, nullptr);
  gemm_bt_k<3, 0><<<dim3(8, 32), 256, 0, stream>>>(bufA, w_sh2, shout,
      4096, 1024, 4096, nullptr, nullptr, nullptr);

  combine_k<<<4096, 256, 0, stream>>>(Hb, shout, eo, tok_row, tok_g, out);
}

// Round 7
// 2363.287 us; speedup vs baseline: 5.3698x; 1.1675x over previous
//
#include <hip/hip_runtime.h>
#include <hip/hip_bf16.h>
#include <cstdint>
#include <cstddef>
#include <math.h>

// ---------- types ----------
typedef __attribute__((ext_vector_type(8))) short bf16x8;
typedef __attribute__((ext_vector_type(4))) float f32x4;
typedef __attribute__((ext_vector_type(4))) short s16x4;

static __device__ __forceinline__ short f2bf(float f) {
  union { __hip_bfloat16 b; short s; } u;
  u.b = __float2bfloat16(f);
  return u.s;
}

static __device__ __forceinline__ void gload_lds16(const short* g, short* l) {
  __builtin_amdgcn_global_load_lds((const __attribute__((address_space(1))) void*)g,
                                   (__attribute__((address_space(3))) void*)l,
                                   16, 0, 0);
}

// ---------- fp32 -> bf16 convert ----------
__global__ __launch_bounds__(256) void cvt_k(const float* __restrict__ src,
                                             short* __restrict__ dst, long n4) {
  long i = (long)blockIdx.x * blockDim.x + threadIdx.x;
  long stride = (long)gridDim.x * blockDim.x;
  for (; i < n4; i += stride) {
    float4 v = ((const float4*)src)[i];
    s16x4 o;
    o.x = f2bf(v.x); o.y = f2bf(v.y); o.z = f2bf(v.z); o.w = f2bf(v.w);
    ((s16x4*)dst)[i] = o;
  }
}

// ---------- RMSNorm fp32 -> fp32 ----------
__global__ __launch_bounds__(256) void rms32_k(const float* __restrict__ x,
                                               const float* __restrict__ w,
                                               float* __restrict__ o) {
  const int row = blockIdx.x, tid = threadIdx.x;
  const float* xr = x + (size_t)row * 1024;
  float4 v = *(const float4*)&xr[tid * 4];
  float ss = v.x * v.x + v.y * v.y + v.z * v.z + v.w * v.w;
#pragma unroll
  for (int off = 32; off; off >>= 1) ss += __shfl_down(ss, off);
  __shared__ float red[4];
  if ((tid & 63) == 0) red[tid >> 6] = ss;
  __syncthreads();
  float rs = rsqrtf((red[0] + red[1] + red[2] + red[3]) * (1.f / 1024.f) + 1e-5f);
  float4 wv = *(const float4*)&w[tid * 4];
  float4 ov;
  ov.x = v.x * rs * wv.x; ov.y = v.y * rs * wv.y;
  ov.z = v.z * rs * wv.z; ov.w = v.w * rs * wv.w;
  *(float4*)&o[(size_t)row * 1024 + tid * 4] = ov;
}

// ---------- RMSNorm fp32 -> bf16 (for MoE expert inputs) ----------
__global__ __launch_bounds__(256) void rms_k(const float* __restrict__ x,
                                             const float* __restrict__ w,
                                             short* __restrict__ obf) {
  const int row = blockIdx.x, tid = threadIdx.x;
  const float* xr = x + (size_t)row * 1024;
  float4 v = *(const float4*)&xr[tid * 4];
  float ss = v.x * v.x + v.y * v.y + v.z * v.z + v.w * v.w;
#pragma unroll
  for (int off = 32; off; off >>= 1) ss += __shfl_down(ss, off);
  __shared__ float red[4];
  if ((tid & 63) == 0) red[tid >> 6] = ss;
  __syncthreads();
  float rs = rsqrtf((red[0] + red[1] + red[2] + red[3]) * (1.f / 1024.f) + 1e-5f);
  float4 wv = *(const float4*)&w[tid * 4];
  s16x4 ob;
  ob.x = f2bf(v.x * rs * wv.x); ob.y = f2bf(v.y * rs * wv.y);
  ob.z = f2bf(v.z * rs * wv.z); ob.w = f2bf(v.w * rs * wv.w);
  *(s16x4*)&obf[(size_t)row * 1024 + tid * 4] = ob;
}

// ---------- fp32 tiled GEMM: C[M,N] = A[M,K] @ B[N,K]^T (PROVEN r5) ----------
// EPI 0: store. 2: +resid store.
template <int EPI>
__global__ __launch_bounds__(256)
void gemm32_k(const float* __restrict__ A, const float* __restrict__ B,
              float* __restrict__ C, const float* __restrict__ resid,
              int M, int N, int K) {
  __shared__ float sA[16][128];
  __shared__ float sB[16][128];
  const int tid = threadIdx.x;
  const int bn = blockIdx.x, bm = blockIdx.y;
  const int tx = tid & 15, ty = tid >> 4;
  const int r4 = tid >> 2;
  const int c4 = (tid & 3) * 4;

  float acc[8][8];
#pragma unroll
  for (int i = 0; i < 8; i++)
#pragma unroll
    for (int j = 0; j < 8; j++) acc[i][j] = 0.f;

  for (int k0 = 0; k0 < K; k0 += 16) {
    __syncthreads();
#pragma unroll
    for (int jj = 0; jj < 2; jj++) {
      const int row = r4 + jj * 64;
      float4 a = *(const float4*)&A[(size_t)(bm * 128 + row) * K + k0 + c4];
      sA[c4 + 0][row] = a.x; sA[c4 + 1][row] = a.y;
      sA[c4 + 2][row] = a.z; sA[c4 + 3][row] = a.w;
      float4 b = *(const float4*)&B[(size_t)(bn * 128 + row) * K + k0 + c4];
      sB[c4 + 0][row] = b.x; sB[c4 + 1][row] = b.y;
      sB[c4 + 2][row] = b.z; sB[c4 + 3][row] = b.w;
    }
    __syncthreads();
#pragma unroll
    for (int k = 0; k < 16; k++) {
      float a8[8], b8[8];
      *(float4*)&a8[0] = *(const float4*)&sA[k][ty * 8];
      *(float4*)&a8[4] = *(const float4*)&sA[k][ty * 8 + 4];
      *(float4*)&b8[0] = *(const float4*)&sB[k][tx * 8];
      *(float4*)&b8[4] = *(const float4*)&sB[k][tx * 8 + 4];
#pragma unroll
      for (int i = 0; i < 8; i++)
#pragma unroll
        for (int j = 0; j < 8; j++) acc[i][j] += a8[i] * b8[j];
    }
  }

#pragma unroll
  for (int i = 0; i < 8; i++) {
    const int rg = bm * 128 + ty * 8 + i;
#pragma unroll
    for (int j = 0; j < 8; j++) {
      const int col = bn * 128 + tx * 8 + j;
      const size_t idx = (size_t)rg * N + col;
      float xv = acc[i][j];
      if (EPI == 0) C[idx] = xv;
      else C[idx] = xv + resid[idx];
    }
  }
}

// ---------- fp32 register-blocked flash attention ----------
// 256 threads; 64 q-rows per block; kv tiles of 64; thread (ty,tx) owns a
// 4q x 4kv score block (phase 1) and 4q x 4d output block (phase 2).
__global__ __launch_bounds__(256)
void attn32t_k(const float* __restrict__ Q, int ldq,
               const float* __restrict__ K, int ldk,
               const float* __restrict__ V, int ldv,
               float* __restrict__ O, int ldo,
               int Tq, int Tkv, int causal, float scale) {
  __shared__ float sQt[64][68];  // Q^T [d][q]
  __shared__ float sKP[64][68];  // K^T [d][kv], reused as P [q][kv]
  __shared__ float sV[64][68];   // V [kv][d]

  const int qb = blockIdx.x, h = blockIdx.y, b = blockIdx.z;
  const int tid = threadIdx.x;
  const int tx = tid & 15, ty = tid >> 4;
  const int hoff = h * 64;
  const int srow = tid >> 2;          // 0..63
  const int scol = (tid & 3) * 4;     // 0,4,8,12

  // stage Q^T once (transpose on store; write banks <=2-way)
  {
    const float* qp = &Q[(size_t)(b * Tq + qb * 64 + srow) * ldq + hoff + scol];
#pragma unroll
    for (int j = 0; j < 4; j++) {
      float4 v = *(const float4*)&qp[j * 16];
      sQt[scol + j * 16 + 0][srow] = v.x;
      sQt[scol + j * 16 + 1][srow] = v.y;
      sQt[scol + j * 16 + 2][srow] = v.z;
      sQt[scol + j * 16 + 3][srow] = v.w;
    }
  }

  float o[4][4];
  float m_run[4], l_run[4];
#pragma unroll
  for (int i = 0; i < 4; i++) {
    m_run[i] = -1e30f; l_run[i] = 0.f;
#pragma unroll
    for (int j = 0; j < 4; j++) o[i][j] = 0.f;
  }

  const int ntiles = causal ? (qb + 1) : (Tkv >> 6);
  for (int kt = 0; kt < ntiles; ++kt) {
    __syncthreads();  // prev phase-2 reads done before restaging
    {
      const float* kp = &K[(size_t)(b * Tkv + kt * 64 + srow) * ldk + hoff + scol];
      const float* vp = &V[(size_t)(b * Tkv + kt * 64 + srow) * ldv + hoff + scol];
#pragma unroll
      for (int j = 0; j < 4; j++) {
        float4 kv = *(const float4*)&kp[j * 16];
        sKP[scol + j * 16 + 0][srow] = kv.x;
        sKP[scol + j * 16 + 1][srow] = kv.y;
        sKP[scol + j * 16 + 2][srow] = kv.z;
        sKP[scol + j * 16 + 3][srow] = kv.w;
        *(float4*)&sV[srow][scol + j * 16] = *(const float4*)&vp[j * 16];
      }
    }
    __syncthreads();

    // phase 1: S(4q x 4kv) = Q K^T
    float s[4][4];
#pragma unroll
    for (int i = 0; i < 4; i++)
#pragma unroll
      for (int j = 0; j < 4; j++) s[i][j] = 0.f;
#pragma unroll 2
    for (int d = 0; d < 64; d++) {
      float4 qv = *(const float4*)&sQt[d][ty * 4];
      float4 kv = *(const float4*)&sKP[d][tx * 4];
      float qa[4] = {qv.x, qv.y, qv.z, qv.w};
      float ka[4] = {kv.x, kv.y, kv.z, kv.w};
#pragma unroll
      for (int i = 0; i < 4; i++)
#pragma unroll
        for (int j = 0; j < 4; j++) s[i][j] += qa[i] * ka[j];
    }

    // scale + mask + online softmax (row reduce over the 16 tx lanes)
#pragma unroll
    for (int i = 0; i < 4; i++) {
      const int qg = qb * 64 + ty * 4 + i;
      float tmax = -1e30f;
#pragma unroll
      for (int j = 0; j < 4; j++) {
        float xv = s[i][j] * scale;
        if (causal && (kt * 64 + tx * 4 + j) > qg) xv = -1e30f;
        s[i][j] = xv;
        tmax = fmaxf(tmax, xv);
      }
      tmax = fmaxf(tmax, __shfl_xor(tmax, 1));
      tmax = fmaxf(tmax, __shfl_xor(tmax, 2));
      tmax = fmaxf(tmax, __shfl_xor(tmax, 4));
      tmax = fmaxf(tmax, __shfl_xor(tmax, 8));
      const float m_new = fmaxf(m_run[i], tmax);
      const float alpha = __expf(m_run[i] - m_new);
      float tsum = 0.f;
#pragma unroll
      for (int j = 0; j < 4; j++) {
        float e = (s[i][j] <= -1e29f) ? 0.f : __expf(s[i][j] - m_new);
        s[i][j] = e; tsum += e;
      }
      tsum += __shfl_xor(tsum, 1);
      tsum += __shfl_xor(tsum, 2);
      tsum += __shfl_xor(tsum, 4);
      tsum += __shfl_xor(tsum, 8);
      l_run[i] = l_run[i] * alpha + tsum;
      m_run[i] = m_new;
#pragma unroll
      for (int j = 0; j < 4; j++) o[i][j] *= alpha;
    }
    __syncthreads();  // all phase-1 reads of sKP done

    // write P [q][kv] into sKP
#pragma unroll
    for (int i = 0; i < 4; i++) {
      float4 pw; pw.x = s[i][0]; pw.y = s[i][1]; pw.z = s[i][2]; pw.w = s[i][3];
      *(float4*)&sKP[ty * 4 + i][tx * 4] = pw;
    }
    __syncthreads();

    // phase 2: O(4q x 4d) += P @ V
#pragma unroll 2
    for (int k4 = 0; k4 < 16; k4++) {
      float4 pv[4];
#pragma unroll
      for (int i = 0; i < 4; i++) pv[i] = *(const float4*)&sKP[ty * 4 + i][k4 * 4];
#pragma unroll
      for (int kk = 0; kk < 4; kk++) {
        float4 vv = *(const float4*)&sV[k4 * 4 + kk][tx * 4];
#pragma unroll
        for (int i = 0; i < 4; i++) {
          const float pk = ((const float*)&pv[i])[kk];
          o[i][0] += pk * vv.x; o[i][1] += pk * vv.y;
          o[i][2] += pk * vv.z; o[i][3] += pk * vv.w;
        }
      }
    }
  }

#pragma unroll
  for (int i = 0; i < 4; i++) {
    const float inv = 1.f / l_run[i];
    float4 ov;
    ov.x = o[i][0] * inv; ov.y = o[i][1] * inv;
    ov.z = o[i][2] * inv; ov.w = o[i][3] * inv;
    *(float4*)&O[(size_t)(b * Tq + qb * 64 + ty * 4 + i) * ldo + hoff + tx * 4] = ov;
  }
}

// ---------- bf16 MFMA GEMM: C[M,N] = A[M,K] @ B[N,K]^T ----------
// MODE 0: dense. MODE 1: A rows gathered via row_map. MODE 2: A rows contiguous from offs[e].
// EPI 1: silu->bf16. EPI 3: fp32 store.
template <int EPI, int MODE>
__global__ __launch_bounds__(256)
void gemm_bt_k(const short* __restrict__ A, const short* __restrict__ B,
               void* C, int M, int N, int K,
               const int* __restrict__ row_map,
               const int* __restrict__ counts,
               const int* __restrict__ offs) {
  __shared__ short sA[128 * 32];
  __shared__ short sB[128 * 32];
  __shared__ int sRow[128];

  const int tid = threadIdx.x;
  const int bn = blockIdx.x, bm = blockIdx.y;
  int base = 0, cnt = M;
  const short* Bp = B;
  if (MODE != 0) {
    const int e = blockIdx.z;
    cnt = counts[e];
    base = offs[e];
    if (bm * 128 >= cnt) return;
    Bp += (size_t)e * N * K;
  }
  const int lane = tid & 63, wv = tid >> 6;
  const int rch = lane >> 2, cch = (lane & 3) << 3;
  const int wr = wv >> 1, wc = wv & 1;
  const int lr = lane & 15, lg = lane >> 4;
  const int c0 = wv * 2, c1 = wv * 2 + 1;

  int ra0 = 0, ra1 = 0;
  if (MODE == 0) {
    ra0 = bm * 128 + c0 * 16 + rch;
    ra1 = bm * 128 + c1 * 16 + rch;
  } else if (MODE == 2) {
    int rl0 = bm * 128 + c0 * 16 + rch, rl1 = bm * 128 + c1 * 16 + rch;
    ra0 = base + ((rl0 < cnt) ? rl0 : 0);
    ra1 = base + ((rl1 < cnt) ? rl1 : 0);
  } else {
    if (tid < 128) {
      int r = bm * 128 + tid;
      sRow[tid] = (r < cnt) ? row_map[base + r] : row_map[base];
    }
    __syncthreads();
    ra0 = sRow[c0 * 16 + rch];
    ra1 = sRow[c1 * 16 + rch];
  }
  const int rb0 = bn * 128 + c0 * 16 + rch, rb1 = bn * 128 + c1 * 16 + rch;

  f32x4 acc[4][4];
#pragma unroll
  for (int m = 0; m < 4; m++)
#pragma unroll
    for (int n = 0; n < 4; n++) acc[m][n] = (f32x4){0.f, 0.f, 0.f, 0.f};

  const int nk = K >> 5;
  for (int kt = 0; kt < nk; ++kt) {
    __syncthreads();
    const int colk = (kt << 5) + cch;
    gload_lds16(A + (size_t)ra0 * K + colk, &sA[c0 * 512]);
    gload_lds16(A + (size_t)ra1 * K + colk, &sA[c1 * 512]);
    gload_lds16(Bp + (size_t)rb0 * K + colk, &sB[c0 * 512]);
    gload_lds16(Bp + (size_t)rb1 * K + colk, &sB[c1 * 512]);
    __syncthreads();
    bf16x8 a[4], b[4];
#pragma unroll
    for (int m = 0; m < 4; m++) a[m] = *(const bf16x8*)&sA[(wr * 64 + m * 16 + lr) * 32 + lg * 8];
#pragma unroll
    for (int n = 0; n < 4; n++) b[n] = *(const bf16x8*)&sB[(wc * 64 + n * 16 + lr) * 32 + lg * 8];
#pragma unroll
    for (int m = 0; m < 4; m++)
#pragma unroll
      for (int n = 0; n < 4; n++)
        acc[m][n] = __builtin_amdgcn_mfma_f32_16x16x32_bf16(a[m], b[n], acc[m][n], 0, 0, 0);
  }

  const int cbase = bn * 128 + wc * 64;
#pragma unroll
  for (int m = 0; m < 4; m++) {
    const int rl = wr * 64 + m * 16 + lg * 4;
#pragma unroll
    for (int n = 0; n < 4; n++) {
      f32x4 v = acc[m][n];
      const int col = cbase + n * 16 + lr;
#pragma unroll
      for (int j = 0; j < 4; j++) {
        const int rloc = bm * 128 + rl + j;
        if (MODE != 0 && rloc >= cnt) continue;
        const size_t rg = (MODE == 0) ? (size_t)rloc : (size_t)(base + rloc);
        const size_t idx = rg * (size_t)N + col;
        float xv = v[j];
        if (EPI == 1) {
          float s = xv / (1.f + __expf(-xv));
          ((short*)C)[idx] = f2bf(s);
        } else {
          ((float*)C)[idx] = xv;
        }
      }
    }
  }
}

// ---------- MoE gating FP64 (from fp32 H): top-2, slots ----------
__global__ __launch_bounds__(256) void gate_k(const float* __restrict__ H,
                                              const float* __restrict__ w3,
                                              const float* __restrict__ gw,
                                              int* counts, int* tok_e, int* tok_s,
                                              float* tok_g) {
  const int token = blockIdx.x * 4 + (threadIdx.x >> 6);
  const int lane = threadIdx.x & 63;
  const float* xr = H + (size_t)token * 1024;
  double a[8] = {0, 0, 0, 0, 0, 0, 0, 0};
  double ss = 0.0;
#pragma unroll
  for (int i = 0; i < 4; i++) {
    float4 xv = *(const float4*)&xr[i * 256 + lane * 4];
    float4 w3v = *(const float4*)&w3[i * 256 + lane * 4];
    ss += (double)xv.x * xv.x + (double)xv.y * xv.y + (double)xv.z * xv.z + (double)xv.w * xv.w;
    double xw0 = (double)xv.x * (double)w3v.x, xw1 = (double)xv.y * (double)w3v.y;
    double xw2 = (double)xv.z * (double)w3v.z, xw3 = (double)xv.w * (double)w3v.w;
#pragma unroll
    for (int e = 0; e < 8; e++) {
      float4 wv = *(const float4*)&gw[e * 1024 + i * 256 + lane * 4];
      a[e] += xw0 * wv.x + xw1 * wv.y + xw2 * wv.z + xw3 * wv.w;
    }
  }
#pragma unroll
  for (int off = 32; off; off >>= 1) {
    ss += __shfl_down(ss, off);
#pragma unroll
    for (int e = 0; e < 8; e++) a[e] += __shfl_down(a[e], off);
  }
  if (lane == 0) {
    double v0 = a[0]; int i0 = 0;
#pragma unroll
    for (int e = 1; e < 8; e++) if (a[e] > v0) { v0 = a[e]; i0 = e; }
    double v1 = -1e300; int i1 = 0;
#pragma unroll
    for (int e = 0; e < 8; e++) if (e != i0 && a[e] > v1) { v1 = a[e]; i1 = e; }
    double rs = 1.0 / sqrt(ss * (1.0 / 1024.0) + 1e-5);
    double t = exp((v1 - v0) * rs);
    double g0 = 1.0 / (1.0 + t);
    int s0 = atomicAdd(&counts[i0], 1);
    int s1 = atomicAdd(&counts[i1], 1);
    tok_e[2 * token] = i0; tok_e[2 * token + 1] = i1;
    tok_s[2 * token] = s0; tok_s[2 * token + 1] = s1;
    tok_g[2 * token] = (float)g0; tok_g[2 * token + 1] = (float)(1.0 - g0);
  }
}

__global__ void offsets_k(const int* counts, int* offs) {
  if (threadIdx.x == 0 && blockIdx.x == 0) {
    int s = 0;
    for (int e = 0; e < 8; e++) { offs[e] = s; s += counts[e]; }
  }
}

__global__ __launch_bounds__(256) void build_rows_k(const int* __restrict__ offs,
                                                    const int* __restrict__ tok_e,
                                                    const int* __restrict__ tok_s,
                                                    int* __restrict__ row_map,
                                                    int* __restrict__ tok_row) {
  int n = blockIdx.x * 256 + threadIdx.x;
  int e0 = tok_e[2 * n], e1 = tok_e[2 * n + 1];
  int r0 = offs[e0] + tok_s[2 * n], r1 = offs[e1] + tok_s[2 * n + 1];
  row_map[r0] = n; row_map[r1] = n;
  tok_row[2 * n] = r0; tok_row[2 * n + 1] = r1;
}

// ---------- final combine: out = H + shared + g0*eo0 + g1*eo1 ----------
__global__ __launch_bounds__(256) void combine_k(const float* __restrict__ H,
                                                 const float* __restrict__ sh,
                                                 const float* __restrict__ eo,
                                                 const int* __restrict__ tok_row,
                                                 const float* __restrict__ tok_g,
                                                 float* __restrict__ out) {
  const int n = blockIdx.x, t = threadIdx.x;
  const int r0 = tok_row[2 * n], r1 = tok_row[2 * n + 1];
  const float g0 = tok_g[2 * n], g1 = tok_g[2 * n + 1];
  const size_t ib = (size_t)n * 1024 + t * 4;
  float4 hv = *(const float4*)&H[ib];
  float4 sv = *(const float4*)&sh[ib];
  float4 a0 = *(const float4*)&eo[(size_t)r0 * 1024 + t * 4];
  float4 a1 = *(const float4*)&eo[(size_t)r1 * 1024 + t * 4];
  float4 ov;
  ov.x = hv.x + sv.x + g0 * a0.x + g1 * a1.x;
  ov.y = hv.y + sv.y + g0 * a0.y + g1 * a1.y;
  ov.z = hv.z + sv.z + g0 * a0.z + g1 * a1.z;
  ov.w = hv.w + sv.w + g0 * a0.w + g1 * a1.w;
  *(float4*)&out[ib] = ov;
}

// ---------- host ----------
extern "C" void kernel_launch(void* const* d_in, const int* in_sizes, int n_in,
                              void* d_out, int out_size, void* d_ws, size_t ws_size,
                              hipStream_t stream) {
  (void)in_sizes; (void)n_in; (void)out_size;
  const float* x     = (const float*)d_in[0];
  const float* enc   = (const float*)d_in[1];
  const float* n1w   = (const float*)d_in[4];
  const float* n2w   = (const float*)d_in[5];
  const float* n3w   = (const float*)d_in[6];
  const float* sa_wq = (const float*)d_in[7];
  const float* sa_wk = (const float*)d_in[8];
  const float* sa_wv = (const float*)d_in[9];
  const float* sa_wo = (const float*)d_in[10];
  const float* ca_wq = (const float*)d_in[11];
  const float* ca_wk = (const float*)d_in[12];
  const float* ca_wv = (const float*)d_in[13];
  const float* ca_wo = (const float*)d_in[14];
  const float* gw    = (const float*)d_in[15];
  const float* e_w1  = (const float*)d_in[16];
  const float* e_w2  = (const float*)d_in[17];
  const float* s_w1  = (const float*)d_in[18];
  const float* s_w2  = (const float*)d_in[19];
  float* out = (float*)d_out;

  char* p = (char*)d_ws;
  size_t off = 0;
  auto alloc = [&](size_t bytes) -> void* {
    void* r = p + off;
    off += (bytes + 255) & ~(size_t)255;
    return r;
  };
  short* w_sh1  = (short*)alloc(4096LL * 1024 * 2);
  short* w_sh2  = (short*)alloc(1024LL * 4096 * 2);
  short* w_e1   = (short*)alloc(8LL * 4096 * 1024 * 2);
  short* w_e2   = (short*)alloc(8LL * 1024 * 4096 * 2);
  short* xn     = (short*)alloc(4096LL * 1024 * 2);
  short* bufA   = (short*)alloc(4096LL * 4096 * 2);   // shared-expert hidden
  short* hbuf   = (short*)alloc(8192LL * 4096 * 2);   // routed hidden
  float* xnf    = (float*)alloc(4096LL * 1024 * 4);
  float* Qb     = (float*)alloc(4096LL * 1024 * 4);
  float* Kb     = (float*)alloc(4096LL * 1024 * 4);
  float* Vb     = (float*)alloc(4096LL * 1024 * 4);
  float* att    = (float*)alloc(4096LL * 1024 * 4);
  float* Hb     = (float*)alloc(4096LL * 1024 * 4);
  float* eo     = (float*)alloc(8192LL * 1024 * 4);
  float* shout  = (float*)alloc(4096LL * 1024 * 4);
  int*   counts = (int*)alloc(8 * 4);
  int*   offs   = (int*)alloc(8 * 4);
  int*   tok_e  = (int*)alloc(4096LL * 2 * 4);
  int*   tok_s  = (int*)alloc(4096LL * 2 * 4);
  float* tok_g  = (float*)alloc(4096LL * 2 * 4);
  int*   tok_row= (int*)alloc(4096LL * 2 * 4);
  int*   row_map= (int*)alloc(8192LL * 4);
  if (off > ws_size) return;

  auto cvt = [&](const float* s, short* d, long n) {
    long n4 = n / 4;
    long g = (n4 + 255) / 256;
    int grid = (int)(g > 4096 ? 4096 : g);
    cvt_k<<<grid, 256, 0, stream>>>(s, d, n4);
  };

  // MoE weights -> bf16
  cvt(s_w1, w_sh1, 4096L * 1024);
  cvt(s_w2, w_sh2, 4096L * 1024);
  cvt(e_w1, w_e1, 8L * 4096 * 1024);
  cvt(e_w2, w_e2, 8L * 1024 * 4096);

  // ---- self attention (fp32: H must stay accurate for gating) ----
  rms32_k<<<4096, 256, 0, stream>>>(x, n1w, xnf);
  gemm32_k<0><<<dim3(8, 32), 256, 0, stream>>>(xnf, sa_wq, Qb, nullptr, 4096, 1024, 1024);
  gemm32_k<0><<<dim3(8, 32), 256, 0, stream>>>(xnf, sa_wk, Kb, nullptr, 4096, 1024, 1024);
  gemm32_k<0><<<dim3(8, 32), 256, 0, stream>>>(xnf, sa_wv, Vb, nullptr, 4096, 1024, 1024);
  attn32t_k<<<dim3(16, 16, 4), 256, 0, stream>>>(Qb, 1024, Kb, 1024, Vb, 1024,
      att, 1024, 1024, 1024, 1, 0.125f);
  gemm32_k<2><<<dim3(8, 32), 256, 0, stream>>>(att, sa_wo, Hb, x, 4096, 1024, 1024);

  // ---- cross attention (fp32) ----
  rms32_k<<<4096, 256, 0, stream>>>(Hb, n2w, xnf);
  gemm32_k<0><<<dim3(8, 32), 256, 0, stream>>>(xnf, ca_wq, Qb, nullptr, 4096, 1024, 1024);
  gemm32_k<0><<<dim3(8, 2), 256, 0, stream>>>(enc, ca_wk, Kb, nullptr, 256, 1024, 1024);
  gemm32_k<0><<<dim3(8, 2), 256, 0, stream>>>(enc, ca_wv, Vb, nullptr, 256, 1024, 1024);
  attn32t_k<<<dim3(16, 16, 4), 256, 0, stream>>>(Qb, 1024, Kb, 1024, Vb, 1024,
      att, 1024, 1024, 64, 0, 0.125f);
  gemm32_k<2><<<dim3(8, 32), 256, 0, stream>>>(att, ca_wo, Hb, Hb, 4096, 1024, 1024);

  // ---- MoE: fp64 gate from fp32 H; bf16 MFMA experts (routed top-2) ----
  rms_k<<<4096, 256, 0, stream>>>(Hb, n3w, xn);
  hipMemsetAsync(counts, 0, 8 * sizeof(int), stream);
  gate_k<<<1024, 256, 0, stream>>>(Hb, n3w, gw, counts, tok_e, tok_s, tok_g);
  offsets_k<<<1, 1, 0, stream>>>(counts, offs);
  build_rows_k<<<16, 256, 0, stream>>>(offs, tok_e, tok_s, row_map, tok_row);
  // expert w1 (gathered rows) + silu -> hbuf (bf16)
  gemm_bt_k<1, 1><<<dim3(32, 32, 8), 256, 0, stream>>>(xn, w_e1, hbuf,
      4096, 4096, 1024, row_map, counts, offs);
  // expert w2 (contiguous rows) -> eo (fp32)
  gemm_bt_k<3, 2><<<dim3(8, 32, 8), 256, 0, stream>>>(hbuf, w_e2, eo,
      4096, 1024, 4096, nullptr, counts, offs);
  // shared expert (dense bf16)
  gemm_bt_k<1, 0><<<dim3(32, 32), 256, 0, stream>>>(xn, w_sh1, bufA,
      4096, 4096, 1024, nullptr, nullptr, nullptr);
  gemm_bt_k<3, 0><<<dim3(8, 32), 256, 0, stream>>>(bufA, w_sh2, shout,
      4096, 1024, 4096, nullptr, nullptr, nullptr);

  combine_k<<<4096, 256, 0, stream>>>(Hb, shout, eo, tok_row, tok_g, out);
}

// Round 8
// 1185.475 us; speedup vs baseline: 10.7049x; 1.9935x over previous
//
#include <hip/hip_runtime.h>
#include <hip/hip_bf16.h>
#include <cstdint>
#include <cstddef>
#include <math.h>

// ---------- types ----------
typedef __attribute__((ext_vector_type(8))) short bf16x8;
typedef __attribute__((ext_vector_type(4))) float f32x4;
typedef __attribute__((ext_vector_type(4))) short s16x4;

static __device__ __forceinline__ short f2bf(float f) {
  union { __hip_bfloat16 b; short s; } u;
  u.b = __float2bfloat16(f);
  return u.s;
}

static __device__ __forceinline__ float bf2f(short s) {
  union { unsigned u; float f; } v;
  v.u = ((unsigned)(unsigned short)s) << 16;
  return v.f;
}

static __device__ __forceinline__ void gload_lds16(const short* g, short* l) {
  __builtin_amdgcn_global_load_lds((const __attribute__((address_space(1))) void*)g,
                                   (__attribute__((address_space(3))) void*)l,
                                   16, 0, 0);
}

// ---------- fp32 -> bf16 convert (plain, for MoE weights) ----------
__global__ __launch_bounds__(256) void cvt_k(const float* __restrict__ src,
                                             short* __restrict__ dst, long n4) {
  long i = (long)blockIdx.x * blockDim.x + threadIdx.x;
  long stride = (long)gridDim.x * blockDim.x;
  for (; i < n4; i += stride) {
    float4 v = ((const float4*)src)[i];
    s16x4 o;
    o.x = f2bf(v.x); o.y = f2bf(v.y); o.z = f2bf(v.z); o.w = f2bf(v.w);
    ((s16x4*)dst)[i] = o;
  }
}

// ---------- fp32 -> bf16 hi/lo split ----------
__global__ __launch_bounds__(256) void cvt2_k(const float* __restrict__ src,
                                              short* __restrict__ hi,
                                              short* __restrict__ lo, long n4) {
  long i = (long)blockIdx.x * blockDim.x + threadIdx.x;
  long stride = (long)gridDim.x * blockDim.x;
  for (; i < n4; i += stride) {
    float4 v = ((const float4*)src)[i];
    s16x4 h, l;
    h.x = f2bf(v.x); l.x = f2bf(v.x - bf2f(h.x));
    h.y = f2bf(v.y); l.y = f2bf(v.y - bf2f(h.y));
    h.z = f2bf(v.z); l.z = f2bf(v.z - bf2f(h.z));
    h.w = f2bf(v.w); l.w = f2bf(v.w - bf2f(h.w));
    ((s16x4*)hi)[i] = h;
    ((s16x4*)lo)[i] = l;
  }
}

// ---------- RMSNorm fp32 -> bf16 hi/lo split ----------
__global__ __launch_bounds__(256) void rms2_k(const float* __restrict__ x,
                                              const float* __restrict__ w,
                                              short* __restrict__ hi,
                                              short* __restrict__ lo) {
  const int row = blockIdx.x, tid = threadIdx.x;
  const float* xr = x + (size_t)row * 1024;
  float4 v = *(const float4*)&xr[tid * 4];
  float ss = v.x * v.x + v.y * v.y + v.z * v.z + v.w * v.w;
#pragma unroll
  for (int off = 32; off; off >>= 1) ss += __shfl_down(ss, off);
  __shared__ float red[4];
  if ((tid & 63) == 0) red[tid >> 6] = ss;
  __syncthreads();
  float rs = rsqrtf((red[0] + red[1] + red[2] + red[3]) * (1.f / 1024.f) + 1e-5f);
  float4 wv = *(const float4*)&w[tid * 4];
  float o0 = v.x * rs * wv.x, o1 = v.y * rs * wv.y;
  float o2 = v.z * rs * wv.z, o3 = v.w * rs * wv.w;
  s16x4 h, l;
  h.x = f2bf(o0); l.x = f2bf(o0 - bf2f(h.x));
  h.y = f2bf(o1); l.y = f2bf(o1 - bf2f(h.y));
  h.z = f2bf(o2); l.z = f2bf(o2 - bf2f(h.z));
  h.w = f2bf(o3); l.w = f2bf(o3 - bf2f(h.w));
  const size_t ib = (size_t)row * 1024 + tid * 4;
  *(s16x4*)&hi[ib] = h;
  *(s16x4*)&lo[ib] = l;
}

// ---------- RMSNorm fp32 -> bf16 (MoE expert input) ----------
__global__ __launch_bounds__(256) void rms_k(const float* __restrict__ x,
                                             const float* __restrict__ w,
                                             short* __restrict__ obf) {
  const int row = blockIdx.x, tid = threadIdx.x;
  const float* xr = x + (size_t)row * 1024;
  float4 v = *(const float4*)&xr[tid * 4];
  float ss = v.x * v.x + v.y * v.y + v.z * v.z + v.w * v.w;
#pragma unroll
  for (int off = 32; off; off >>= 1) ss += __shfl_down(ss, off);
  __shared__ float red[4];
  if ((tid & 63) == 0) red[tid >> 6] = ss;
  __syncthreads();
  float rs = rsqrtf((red[0] + red[1] + red[2] + red[3]) * (1.f / 1024.f) + 1e-5f);
  float4 wv = *(const float4*)&w[tid * 4];
  s16x4 ob;
  ob.x = f2bf(v.x * rs * wv.x); ob.y = f2bf(v.y * rs * wv.y);
  ob.z = f2bf(v.z * rs * wv.z); ob.w = f2bf(v.w * rs * wv.w);
  *(s16x4*)&obf[(size_t)row * 1024 + tid * 4] = ob;
}

// ---------- bf16x3 split MFMA GEMM: C[M,N] = A@B^T, fp32-equivalent precision ----------
// A = Ah+Al, B = Bh+Bl. acc += Ah*Bh + Al*Bh + Ah*Bl.
// EPI 0: fp32 store. EPI 2: fp32 +resid store.
template <int EPI>
__global__ __launch_bounds__(256)
void gemm3_k(const short* __restrict__ Ah, const short* __restrict__ Al,
             const short* __restrict__ Bh, const short* __restrict__ Bl,
             float* __restrict__ C, const float* __restrict__ resid,
             int M, int N, int K) {
  __shared__ short sAh[128 * 32];
  __shared__ short sAl[128 * 32];
  __shared__ short sBh[128 * 32];
  __shared__ short sBl[128 * 32];

  const int tid = threadIdx.x;
  const int bn = blockIdx.x, bm = blockIdx.y;
  const int lane = tid & 63, wv = tid >> 6;
  const int rch = lane >> 2, cch = (lane & 3) << 3;
  const int wr = wv >> 1, wc = wv & 1;
  const int lr = lane & 15, lg = lane >> 4;
  const int c0 = wv * 2, c1 = wv * 2 + 1;

  const int ra0 = bm * 128 + c0 * 16 + rch;
  const int ra1 = bm * 128 + c1 * 16 + rch;
  const int rb0 = bn * 128 + c0 * 16 + rch, rb1 = bn * 128 + c1 * 16 + rch;

  f32x4 acc[4][4];
#pragma unroll
  for (int m = 0; m < 4; m++)
#pragma unroll
    for (int n = 0; n < 4; n++) acc[m][n] = (f32x4){0.f, 0.f, 0.f, 0.f};

  const int nk = K >> 5;
  for (int kt = 0; kt < nk; ++kt) {
    __syncthreads();
    const int colk = (kt << 5) + cch;
    gload_lds16(Ah + (size_t)ra0 * K + colk, &sAh[c0 * 512]);
    gload_lds16(Ah + (size_t)ra1 * K + colk, &sAh[c1 * 512]);
    gload_lds16(Al + (size_t)ra0 * K + colk, &sAl[c0 * 512]);
    gload_lds16(Al + (size_t)ra1 * K + colk, &sAl[c1 * 512]);
    gload_lds16(Bh + (size_t)rb0 * K + colk, &sBh[c0 * 512]);
    gload_lds16(Bh + (size_t)rb1 * K + colk, &sBh[c1 * 512]);
    gload_lds16(Bl + (size_t)rb0 * K + colk, &sBl[c0 * 512]);
    gload_lds16(Bl + (size_t)rb1 * K + colk, &sBl[c1 * 512]);
    __syncthreads();
    bf16x8 ah[4], al[4], bh[4], bl[4];
#pragma unroll
    for (int m = 0; m < 4; m++) {
      const int o = (wr * 64 + m * 16 + lr) * 32 + lg * 8;
      ah[m] = *(const bf16x8*)&sAh[o];
      al[m] = *(const bf16x8*)&sAl[o];
    }
#pragma unroll
    for (int n = 0; n < 4; n++) {
      const int o = (wc * 64 + n * 16 + lr) * 32 + lg * 8;
      bh[n] = *(const bf16x8*)&sBh[o];
      bl[n] = *(const bf16x8*)&sBl[o];
    }
#pragma unroll
    for (int m = 0; m < 4; m++)
#pragma unroll
      for (int n = 0; n < 4; n++) {
        acc[m][n] = __builtin_amdgcn_mfma_f32_16x16x32_bf16(ah[m], bh[n], acc[m][n], 0, 0, 0);
        acc[m][n] = __builtin_amdgcn_mfma_f32_16x16x32_bf16(al[m], bh[n], acc[m][n], 0, 0, 0);
        acc[m][n] = __builtin_amdgcn_mfma_f32_16x16x32_bf16(ah[m], bl[n], acc[m][n], 0, 0, 0);
      }
  }

  const int cbase = bn * 128 + wc * 64;
#pragma unroll
  for (int m = 0; m < 4; m++) {
    const int rl = bm * 128 + wr * 64 + m * 16 + lg * 4;
#pragma unroll
    for (int n = 0; n < 4; n++) {
      f32x4 v = acc[m][n];
      const int col = cbase + n * 16 + lr;
#pragma unroll
      for (int j = 0; j < 4; j++) {
        const size_t idx = (size_t)(rl + j) * N + col;
        if (EPI == 0) C[idx] = v[j];
        else C[idx] = v[j] + resid[idx];
      }
    }
  }
}

// ---------- fp32 register-blocked flash attention (hi/lo bf16 output) ----------
// Flattened heavy-first grid: 1024 blocks; qb=15-(idx>>6), h=(idx>>2)&15, b=idx&3.
__global__ __launch_bounds__(256)
void attn32t_k(const float* __restrict__ Q, int ldq,
               const float* __restrict__ K, int ldk,
               const float* __restrict__ V, int ldv,
               short* __restrict__ Oh, short* __restrict__ Ol, int ldo,
               int Tq, int Tkv, int causal, float scale) {
  __shared__ float sQt[64][68];
  __shared__ float sKP[64][68];
  __shared__ float sV[64][68];

  const int idx = blockIdx.x;
  const int qb = 15 - (idx >> 6);
  const int h = (idx >> 2) & 15;
  const int b = idx & 3;
  const int tid = threadIdx.x;
  const int tx = tid & 15, ty = tid >> 4;
  const int hoff = h * 64;
  const int srow = tid >> 2;
  const int scol = (tid & 3) * 4;

  {
    const float* qp = &Q[(size_t)(b * Tq + qb * 64 + srow) * ldq + hoff + scol];
#pragma unroll
    for (int j = 0; j < 4; j++) {
      float4 v = *(const float4*)&qp[j * 16];
      sQt[scol + j * 16 + 0][srow] = v.x;
      sQt[scol + j * 16 + 1][srow] = v.y;
      sQt[scol + j * 16 + 2][srow] = v.z;
      sQt[scol + j * 16 + 3][srow] = v.w;
    }
  }

  float o[4][4];
  float m_run[4], l_run[4];
#pragma unroll
  for (int i = 0; i < 4; i++) {
    m_run[i] = -1e30f; l_run[i] = 0.f;
#pragma unroll
    for (int j = 0; j < 4; j++) o[i][j] = 0.f;
  }

  const int ntiles = causal ? (qb + 1) : (Tkv >> 6);
  for (int kt = 0; kt < ntiles; ++kt) {
    __syncthreads();
    {
      const float* kp = &K[(size_t)(b * Tkv + kt * 64 + srow) * ldk + hoff + scol];
      const float* vp = &V[(size_t)(b * Tkv + kt * 64 + srow) * ldv + hoff + scol];
#pragma unroll
      for (int j = 0; j < 4; j++) {
        float4 kv = *(const float4*)&kp[j * 16];
        sKP[scol + j * 16 + 0][srow] = kv.x;
        sKP[scol + j * 16 + 1][srow] = kv.y;
        sKP[scol + j * 16 + 2][srow] = kv.z;
        sKP[scol + j * 16 + 3][srow] = kv.w;
        *(float4*)&sV[srow][scol + j * 16] = *(const float4*)&vp[j * 16];
      }
    }
    __syncthreads();

    float s[4][4];
#pragma unroll
    for (int i = 0; i < 4; i++)
#pragma unroll
      for (int j = 0; j < 4; j++) s[i][j] = 0.f;
#pragma unroll 2
    for (int d = 0; d < 64; d++) {
      float4 qv = *(const float4*)&sQt[d][ty * 4];
      float4 kv = *(const float4*)&sKP[d][tx * 4];
      float qa[4] = {qv.x, qv.y, qv.z, qv.w};
      float ka[4] = {kv.x, kv.y, kv.z, kv.w};
#pragma unroll
      for (int i = 0; i < 4; i++)
#pragma unroll
        for (int j = 0; j < 4; j++) s[i][j] += qa[i] * ka[j];
    }

#pragma unroll
    for (int i = 0; i < 4; i++) {
      const int qg = qb * 64 + ty * 4 + i;
      float tmax = -1e30f;
#pragma unroll
      for (int j = 0; j < 4; j++) {
        float xv = s[i][j] * scale;
        if (causal && (kt * 64 + tx * 4 + j) > qg) xv = -1e30f;
        s[i][j] = xv;
        tmax = fmaxf(tmax, xv);
      }
      tmax = fmaxf(tmax, __shfl_xor(tmax, 1));
      tmax = fmaxf(tmax, __shfl_xor(tmax, 2));
      tmax = fmaxf(tmax, __shfl_xor(tmax, 4));
      tmax = fmaxf(tmax, __shfl_xor(tmax, 8));
      const float m_new = fmaxf(m_run[i], tmax);
      const float alpha = __expf(m_run[i] - m_new);
      float tsum = 0.f;
#pragma unroll
      for (int j = 0; j < 4; j++) {
        float e = (s[i][j] <= -1e29f) ? 0.f : __expf(s[i][j] - m_new);
        s[i][j] = e; tsum += e;
      }
      tsum += __shfl_xor(tsum, 1);
      tsum += __shfl_xor(tsum, 2);
      tsum += __shfl_xor(tsum, 4);
      tsum += __shfl_xor(tsum, 8);
      l_run[i] = l_run[i] * alpha + tsum;
      m_run[i] = m_new;
#pragma unroll
      for (int j = 0; j < 4; j++) o[i][j] *= alpha;
    }
    __syncthreads();

#pragma unroll
    for (int i = 0; i < 4; i++) {
      float4 pw; pw.x = s[i][0]; pw.y = s[i][1]; pw.z = s[i][2]; pw.w = s[i][3];
      *(float4*)&sKP[ty * 4 + i][tx * 4] = pw;
    }
    __syncthreads();

#pragma unroll 2
    for (int k4 = 0; k4 < 16; k4++) {
      float4 pv[4];
#pragma unroll
      for (int i = 0; i < 4; i++) pv[i] = *(const float4*)&sKP[ty * 4 + i][k4 * 4];
#pragma unroll
      for (int kk = 0; kk < 4; kk++) {
        float4 vv = *(const float4*)&sV[k4 * 4 + kk][tx * 4];
#pragma unroll
        for (int i = 0; i < 4; i++) {
          const float pk = ((const float*)&pv[i])[kk];
          o[i][0] += pk * vv.x; o[i][1] += pk * vv.y;
          o[i][2] += pk * vv.z; o[i][3] += pk * vv.w;
        }
      }
    }
  }

#pragma unroll
  for (int i = 0; i < 4; i++) {
    const float inv = 1.f / l_run[i];
    const size_t ob = (size_t)(b * Tq + qb * 64 + ty * 4 + i) * ldo + hoff + tx * 4;
    s16x4 hh, ll;
    float v0 = o[i][0] * inv, v1 = o[i][1] * inv, v2 = o[i][2] * inv, v3 = o[i][3] * inv;
    hh.x = f2bf(v0); ll.x = f2bf(v0 - bf2f(hh.x));
    hh.y = f2bf(v1); ll.y = f2bf(v1 - bf2f(hh.y));
    hh.z = f2bf(v2); ll.z = f2bf(v2 - bf2f(hh.z));
    hh.w = f2bf(v3); ll.w = f2bf(v3 - bf2f(hh.w));
    *(s16x4*)&Oh[ob] = hh;
    *(s16x4*)&Ol[ob] = ll;
  }
}

// ---------- bf16 MFMA GEMM (MoE): C[M,N] = A@B^T ----------
// MODE 0: dense. MODE 1: A rows gathered. MODE 2: A rows contiguous from offs[e].
// EPI 1: silu->bf16. EPI 3: fp32 store.
template <int EPI, int MODE>
__global__ __launch_bounds__(256)
void gemm_bt_k(const short* __restrict__ A, const short* __restrict__ B,
               void* C, int M, int N, int K,
               const int* __restrict__ row_map,
               const int* __restrict__ counts,
               const int* __restrict__ offs) {
  __shared__ short sA[128 * 32];
  __shared__ short sB[128 * 32];
  __shared__ int sRow[128];

  const int tid = threadIdx.x;
  const int bn = blockIdx.x, bm = blockIdx.y;
  int base = 0, cnt = M;
  const short* Bp = B;
  if (MODE != 0) {
    const int e = blockIdx.z;
    cnt = counts[e];
    base = offs[e];
    if (bm * 128 >= cnt) return;
    Bp += (size_t)e * N * K;
  }
  const int lane = tid & 63, wv = tid >> 6;
  const int rch = lane >> 2, cch = (lane & 3) << 3;
  const int wr = wv >> 1, wc = wv & 1;
  const int lr = lane & 15, lg = lane >> 4;
  const int c0 = wv * 2, c1 = wv * 2 + 1;

  int ra0 = 0, ra1 = 0;
  if (MODE == 0) {
    ra0 = bm * 128 + c0 * 16 + rch;
    ra1 = bm * 128 + c1 * 16 + rch;
  } else if (MODE == 2) {
    int rl0 = bm * 128 + c0 * 16 + rch, rl1 = bm * 128 + c1 * 16 + rch;
    ra0 = base + ((rl0 < cnt) ? rl0 : 0);
    ra1 = base + ((rl1 < cnt) ? rl1 : 0);
  } else {
    if (tid < 128) {
      int r = bm * 128 + tid;
      sRow[tid] = (r < cnt) ? row_map[base + r] : row_map[base];
    }
    __syncthreads();
    ra0 = sRow[c0 * 16 + rch];
    ra1 = sRow[c1 * 16 + rch];
  }
  const int rb0 = bn * 128 + c0 * 16 + rch, rb1 = bn * 128 + c1 * 16 + rch;

  f32x4 acc[4][4];
#pragma unroll
  for (int m = 0; m < 4; m++)
#pragma unroll
    for (int n = 0; n < 4; n++) acc[m][n] = (f32x4){0.f, 0.f, 0.f, 0.f};

  const int nk = K >> 5;
  for (int kt = 0; kt < nk; ++kt) {
    __syncthreads();
    const int colk = (kt << 5) + cch;
    gload_lds16(A + (size_t)ra0 * K + colk, &sA[c0 * 512]);
    gload_lds16(A + (size_t)ra1 * K + colk, &sA[c1 * 512]);
    gload_lds16(Bp + (size_t)rb0 * K + colk, &sB[c0 * 512]);
    gload_lds16(Bp + (size_t)rb1 * K + colk, &sB[c1 * 512]);
    __syncthreads();
    bf16x8 a[4], b[4];
#pragma unroll
    for (int m = 0; m < 4; m++) a[m] = *(const bf16x8*)&sA[(wr * 64 + m * 16 + lr) * 32 + lg * 8];
#pragma unroll
    for (int n = 0; n < 4; n++) b[n] = *(const bf16x8*)&sB[(wc * 64 + n * 16 + lr) * 32 + lg * 8];
#pragma unroll
    for (int m = 0; m < 4; m++)
#pragma unroll
      for (int n = 0; n < 4; n++)
        acc[m][n] = __builtin_amdgcn_mfma_f32_16x16x32_bf16(a[m], b[n], acc[m][n], 0, 0, 0);
  }

  const int cbase = bn * 128 + wc * 64;
#pragma unroll
  for (int m = 0; m < 4; m++) {
    const int rl = wr * 64 + m * 16 + lg * 4;
#pragma unroll
    for (int n = 0; n < 4; n++) {
      f32x4 v = acc[m][n];
      const int col = cbase + n * 16 + lr;
#pragma unroll
      for (int j = 0; j < 4; j++) {
        const int rloc = bm * 128 + rl + j;
        if (MODE != 0 && rloc >= cnt) continue;
        const size_t rg = (MODE == 0) ? (size_t)rloc : (size_t)(base + rloc);
        const size_t idx = rg * (size_t)N + col;
        float xv = v[j];
        if (EPI == 1) {
          float s = xv / (1.f + __expf(-xv));
          ((short*)C)[idx] = f2bf(s);
        } else {
          ((float*)C)[idx] = xv;
        }
      }
    }
  }
}

// ---------- MoE gating FP64 ----------
__global__ __launch_bounds__(256) void gate_k(const float* __restrict__ H,
                                              const float* __restrict__ w3,
                                              const float* __restrict__ gw,
                                              int* counts, int* tok_e, int* tok_s,
                                              float* tok_g) {
  const int token = blockIdx.x * 4 + (threadIdx.x >> 6);
  const int lane = threadIdx.x & 63;
  const float* xr = H + (size_t)token * 1024;
  double a[8] = {0, 0, 0, 0, 0, 0, 0, 0};
  double ss = 0.0;
#pragma unroll
  for (int i = 0; i < 4; i++) {
    float4 xv = *(const float4*)&xr[i * 256 + lane * 4];
    float4 w3v = *(const float4*)&w3[i * 256 + lane * 4];
    ss += (double)xv.x * xv.x + (double)xv.y * xv.y + (double)xv.z * xv.z + (double)xv.w * xv.w;
    double xw0 = (double)xv.x * (double)w3v.x, xw1 = (double)xv.y * (double)w3v.y;
    double xw2 = (double)xv.z * (double)w3v.z, xw3 = (double)xv.w * (double)w3v.w;
#pragma unroll
    for (int e = 0; e < 8; e++) {
      float4 wv = *(const float4*)&gw[e * 1024 + i * 256 + lane * 4];
      a[e] += xw0 * wv.x + xw1 * wv.y + xw2 * wv.z + xw3 * wv.w;
    }
  }
#pragma unroll
  for (int off = 32; off; off >>= 1) {
    ss += __shfl_down(ss, off);
#pragma unroll
    for (int e = 0; e < 8; e++) a[e] += __shfl_down(a[e], off);
  }
  if (lane == 0) {
    double v0 = a[0]; int i0 = 0;
#pragma unroll
    for (int e = 1; e < 8; e++) if (a[e] > v0) { v0 = a[e]; i0 = e; }
    double v1 = -1e300; int i1 = 0;
#pragma unroll
    for (int e = 0; e < 8; e++) if (e != i0 && a[e] > v1) { v1 = a[e]; i1 = e; }
    double rs = 1.0 / sqrt(ss * (1.0 / 1024.0) + 1e-5);
    double t = exp((v1 - v0) * rs);
    double g0 = 1.0 / (1.0 + t);
    int s0 = atomicAdd(&counts[i0], 1);
    int s1 = atomicAdd(&counts[i1], 1);
    tok_e[2 * token] = i0; tok_e[2 * token + 1] = i1;
    tok_s[2 * token] = s0; tok_s[2 * token + 1] = s1;
    tok_g[2 * token] = (float)g0; tok_g[2 * token + 1] = (float)(1.0 - g0);
  }
}

__global__ void offsets_k(const int* counts, int* offs) {
  if (threadIdx.x == 0 && blockIdx.x == 0) {
    int s = 0;
    for (int e = 0; e < 8; e++) { offs[e] = s; s += counts[e]; }
  }
}

__global__ __launch_bounds__(256) void build_rows_k(const int* __restrict__ offs,
                                                    const int* __restrict__ tok_e,
                                                    const int* __restrict__ tok_s,
                                                    int* __restrict__ row_map,
                                                    int* __restrict__ tok_row) {
  int n = blockIdx.x * 256 + threadIdx.x;
  int e0 = tok_e[2 * n], e1 = tok_e[2 * n + 1];
  int r0 = offs[e0] + tok_s[2 * n], r1 = offs[e1] + tok_s[2 * n + 1];
  row_map[r0] = n; row_map[r1] = n;
  tok_row[2 * n] = r0; tok_row[2 * n + 1] = r1;
}

// ---------- final combine ----------
__global__ __launch_bounds__(256) void combine_k(const float* __restrict__ H,
                                                 const float* __restrict__ sh,
                                                 const float* __restrict__ eo,
                                                 const int* __restrict__ tok_row,
                                                 const float* __restrict__ tok_g,
                                                 float* __restrict__ out) {
  const int n = blockIdx.x, t = threadIdx.x;
  const int r0 = tok_row[2 * n], r1 = tok_row[2 * n + 1];
  const float g0 = tok_g[2 * n], g1 = tok_g[2 * n + 1];
  const size_t ib = (size_t)n * 1024 + t * 4;
  float4 hv = *(const float4*)&H[ib];
  float4 sv = *(const float4*)&sh[ib];
  float4 a0 = *(const float4*)&eo[(size_t)r0 * 1024 + t * 4];
  float4 a1 = *(const float4*)&eo[(size_t)r1 * 1024 + t * 4];
  float4 ov;
  ov.x = hv.x + sv.x + g0 * a0.x + g1 * a1.x;
  ov.y = hv.y + sv.y + g0 * a0.y + g1 * a1.y;
  ov.z = hv.z + sv.z + g0 * a0.z + g1 * a1.z;
  ov.w = hv.w + sv.w + g0 * a0.w + g1 * a1.w;
  *(float4*)&out[ib] = ov;
}

// ---------- host ----------
extern "C" void kernel_launch(void* const* d_in, const int* in_sizes, int n_in,
                              void* d_out, int out_size, void* d_ws, size_t ws_size,
                              hipStream_t stream) {
  (void)in_sizes; (void)n_in; (void)out_size;
  const float* x     = (const float*)d_in[0];
  const float* enc   = (const float*)d_in[1];
  const float* n1w   = (const float*)d_in[4];
  const float* n2w   = (const float*)d_in[5];
  const float* n3w   = (const float*)d_in[6];
  const float* sa_wq = (const float*)d_in[7];
  const float* sa_wk = (const float*)d_in[8];
  const float* sa_wv = (const float*)d_in[9];
  const float* sa_wo = (const float*)d_in[10];
  const float* ca_wq = (const float*)d_in[11];
  const float* ca_wk = (const float*)d_in[12];
  const float* ca_wv = (const float*)d_in[13];
  const float* ca_wo = (const float*)d_in[14];
  const float* gw    = (const float*)d_in[15];
  const float* e_w1  = (const float*)d_in[16];
  const float* e_w2  = (const float*)d_in[17];
  const float* s_w1  = (const float*)d_in[18];
  const float* s_w2  = (const float*)d_in[19];
  float* out = (float*)d_out;

  char* p = (char*)d_ws;
  size_t off = 0;
  auto alloc = [&](size_t bytes) -> void* {
    void* r = p + off;
    off += (bytes + 255) & ~(size_t)255;
    return r;
  };
  // bf16 MoE weights
  short* w_sh1  = (short*)alloc(4096LL * 1024 * 2);
  short* w_sh2  = (short*)alloc(1024LL * 4096 * 2);
  short* w_e1   = (short*)alloc(8LL * 4096 * 1024 * 2);
  short* w_e2   = (short*)alloc(8LL * 1024 * 4096 * 2);
  short* xn     = (short*)alloc(4096LL * 1024 * 2);
  short* hbuf   = (short*)alloc(8192LL * 4096 * 2);   // routed hidden; first 32MB reused as shared hidden
  short* bufA   = hbuf;                                // alias (sequential use)
  // fp32 activations
  float* qkvb   = (float*)alloc(4096LL * 3072 * 4);   // self QKV; cross Q (ld1024); encKV at +8M floats
  float* Hb     = (float*)alloc(4096LL * 1024 * 4);
  float* eo     = (float*)alloc(8192LL * 1024 * 4);
  float* shout  = (float*)alloc(4096LL * 1024 * 4);
  // hi/lo splits
  short* xh     = (short*)alloc(4096LL * 1024 * 2);   // act split (rms out / attn out)
  short* xl     = (short*)alloc(4096LL * 1024 * 2);
  short* ench   = (short*)alloc(256LL * 1024 * 2);
  short* encl   = (short*)alloc(256LL * 1024 * 2);
  short* wsh    = (short*)alloc(3072LL * 1024 * 2);   // weight split scratch (sequential reuse)
  short* wsl    = (short*)alloc(3072LL * 1024 * 2);
  // routing
  int*   counts = (int*)alloc(8 * 4);
  int*   offs   = (int*)alloc(8 * 4);
  int*   tok_e  = (int*)alloc(4096LL * 2 * 4);
  int*   tok_s  = (int*)alloc(4096LL * 2 * 4);
  float* tok_g  = (float*)alloc(4096LL * 2 * 4);
  int*   tok_row= (int*)alloc(4096LL * 2 * 4);
  int*   row_map= (int*)alloc(8192LL * 4);
  if (off > ws_size) return;

  float* crossQ = qkvb;                    // [4096][1024]
  float* encKV  = qkvb + 8388608;          // [256][2048]

  auto cvt = [&](const float* s, short* d, long n) {
    long n4 = n / 4;
    long g = (n4 + 255) / 256;
    int grid = (int)(g > 4096 ? 4096 : g);
    cvt_k<<<grid, 256, 0, stream>>>(s, d, n4);
  };
  auto cvt2 = [&](const float* s, short* h, short* l, long n) {
    long n4 = n / 4;
    long g = (n4 + 255) / 256;
    int grid = (int)(g > 4096 ? 4096 : g);
    cvt2_k<<<grid, 256, 0, stream>>>(s, h, l, n4);
  };

  // MoE weights -> bf16 (plain)
  cvt(s_w1, w_sh1, 4096L * 1024);
  cvt(s_w2, w_sh2, 4096L * 1024);
  cvt(e_w1, w_e1, 8L * 4096 * 1024);
  cvt(e_w2, w_e2, 8L * 1024 * 4096);
  // encoder split (used by cross KV)
  cvt2(enc, ench, encl, 256L * 1024);

  // ---- self attention ----
  rms2_k<<<4096, 256, 0, stream>>>(x, n1w, xh, xl);
  cvt2(sa_wq, wsh, wsl, 1024L * 1024);
  cvt2(sa_wk, wsh + 1048576, wsl + 1048576, 1024L * 1024);
  cvt2(sa_wv, wsh + 2097152, wsl + 2097152, 1024L * 1024);
  gemm3_k<0><<<dim3(24, 32), 256, 0, stream>>>(xh, xl, wsh, wsl, qkvb, nullptr,
      4096, 3072, 1024);
  attn32t_k<<<1024, 256, 0, stream>>>(qkvb, 3072, qkvb + 1024, 3072, qkvb + 2048, 3072,
      xh, xl, 1024, 1024, 1024, 1, 0.125f);
  cvt2(sa_wo, wsh, wsl, 1024L * 1024);
  gemm3_k<2><<<dim3(8, 32), 256, 0, stream>>>(xh, xl, wsh, wsl, Hb, x,
      4096, 1024, 1024);

  // ---- cross attention ----
  rms2_k<<<4096, 256, 0, stream>>>(Hb, n2w, xh, xl);
  cvt2(ca_wq, wsh, wsl, 1024L * 1024);
  gemm3_k<0><<<dim3(8, 32), 256, 0, stream>>>(xh, xl, wsh, wsl, crossQ, nullptr,
      4096, 1024, 1024);
  cvt2(ca_wk, wsh, wsl, 1024L * 1024);
  cvt2(ca_wv, wsh + 1048576, wsl + 1048576, 1024L * 1024);
  gemm3_k<0><<<dim3(16, 2), 256, 0, stream>>>(ench, encl, wsh, wsl, encKV, nullptr,
      256, 2048, 1024);
  attn32t_k<<<1024, 256, 0, stream>>>(crossQ, 1024, encKV, 2048, encKV + 1024, 2048,
      xh, xl, 1024, 1024, 64, 0, 0.125f);
  cvt2(ca_wo, wsh, wsl, 1024L * 1024);
  gemm3_k<2><<<dim3(8, 32), 256, 0, stream>>>(xh, xl, wsh, wsl, Hb, Hb,
      4096, 1024, 1024);

  // ---- MoE: fp64 gate from fp32 H; bf16 MFMA experts (routed top-2) ----
  rms_k<<<4096, 256, 0, stream>>>(Hb, n3w, xn);
  hipMemsetAsync(counts, 0, 8 * sizeof(int), stream);
  gate_k<<<1024, 256, 0, stream>>>(Hb, n3w, gw, counts, tok_e, tok_s, tok_g);
  offsets_k<<<1, 1, 0, stream>>>(counts, offs);
  build_rows_k<<<16, 256, 0, stream>>>(offs, tok_e, tok_s, row_map, tok_row);
  gemm_bt_k<1, 1><<<dim3(32, 32, 8), 256, 0, stream>>>(xn, w_e1, hbuf,
      4096, 4096, 1024, row_map, counts, offs);
  gemm_bt_k<3, 2><<<dim3(8, 32, 8), 256, 0, stream>>>(hbuf, w_e2, eo,
      4096, 1024, 4096, nullptr, counts, offs);
  gemm_bt_k<1, 0><<<dim3(32, 32), 256, 0, stream>>>(xn, w_sh1, bufA,
      4096, 4096, 1024, nullptr, nullptr, nullptr);
  gemm_bt_k<3, 0><<<dim3(8, 32), 256, 0, stream>>>(bufA, w_sh2, shout,
      4096, 1024, 4096, nullptr, nullptr, nullptr);

  combine_k<<<4096, 256, 0, stream>>>(Hb, shout, eo, tok_row, tok_g, out);
}

// Round 9
// 1075.154 us; speedup vs baseline: 11.8033x; 1.1026x over previous
//
#include <hip/hip_runtime.h>
#include <hip/hip_bf16.h>
#include <cstdint>
#include <cstddef>
#include <math.h>

// ---------- types ----------
typedef __attribute__((ext_vector_type(8))) short bf16x8;
typedef __attribute__((ext_vector_type(4))) float f32x4;
typedef __attribute__((ext_vector_type(4))) short s16x4;

static __device__ __forceinline__ short f2bf(float f) {
  union { __hip_bfloat16 b; short s; } u;
  u.b = __float2bfloat16(f);
  return u.s;
}

static __device__ __forceinline__ float bf2f(short s) {
  union { unsigned u; float f; } v;
  v.u = ((unsigned)(unsigned short)s) << 16;
  return v.f;
}

static __device__ __forceinline__ void gload_lds16(const short* g, short* l) {
  __builtin_amdgcn_global_load_lds((const __attribute__((address_space(1))) void*)g,
                                   (__attribute__((address_space(3))) void*)l,
                                   16, 0, 0);
}

// ---------- fp32 -> bf16 convert (plain, MoE weights) ----------
__global__ __launch_bounds__(256) void cvt_k(const float* __restrict__ src,
                                             short* __restrict__ dst, long n4) {
  long i = (long)blockIdx.x * blockDim.x + threadIdx.x;
  long stride = (long)gridDim.x * blockDim.x;
  for (; i < n4; i += stride) {
    float4 v = ((const float4*)src)[i];
    s16x4 o;
    o.x = f2bf(v.x); o.y = f2bf(v.y); o.z = f2bf(v.z); o.w = f2bf(v.w);
    ((s16x4*)dst)[i] = o;
  }
}

// ---------- fp32 -> bf16 hi/lo split ----------
__global__ __launch_bounds__(256) void cvt2_k(const float* __restrict__ src,
                                              short* __restrict__ hi,
                                              short* __restrict__ lo, long n4) {
  long i = (long)blockIdx.x * blockDim.x + threadIdx.x;
  long stride = (long)gridDim.x * blockDim.x;
  for (; i < n4; i += stride) {
    float4 v = ((const float4*)src)[i];
    s16x4 h, l;
    h.x = f2bf(v.x); l.x = f2bf(v.x - bf2f(h.x));
    h.y = f2bf(v.y); l.y = f2bf(v.y - bf2f(h.y));
    h.z = f2bf(v.z); l.z = f2bf(v.z - bf2f(h.z));
    h.w = f2bf(v.w); l.w = f2bf(v.w - bf2f(h.w));
    ((s16x4*)hi)[i] = h;
    ((s16x4*)lo)[i] = l;
  }
}

// ---------- RMSNorm fp32 -> bf16 hi/lo split ----------
__global__ __launch_bounds__(256) void rms2_k(const float* __restrict__ x,
                                              const float* __restrict__ w,
                                              short* __restrict__ hi,
                                              short* __restrict__ lo) {
  const int row = blockIdx.x, tid = threadIdx.x;
  const float* xr = x + (size_t)row * 1024;
  float4 v = *(const float4*)&xr[tid * 4];
  float ss = v.x * v.x + v.y * v.y + v.z * v.z + v.w * v.w;
#pragma unroll
  for (int off = 32; off; off >>= 1) ss += __shfl_down(ss, off);
  __shared__ float red[4];
  if ((tid & 63) == 0) red[tid >> 6] = ss;
  __syncthreads();
  float rs = rsqrtf((red[0] + red[1] + red[2] + red[3]) * (1.f / 1024.f) + 1e-5f);
  float4 wv = *(const float4*)&w[tid * 4];
  float o0 = v.x * rs * wv.x, o1 = v.y * rs * wv.y;
  float o2 = v.z * rs * wv.z, o3 = v.w * rs * wv.w;
  s16x4 h, l;
  h.x = f2bf(o0); l.x = f2bf(o0 - bf2f(h.x));
  h.y = f2bf(o1); l.y = f2bf(o1 - bf2f(h.y));
  h.z = f2bf(o2); l.z = f2bf(o2 - bf2f(h.z));
  h.w = f2bf(o3); l.w = f2bf(o3 - bf2f(h.w));
  const size_t ib = (size_t)row * 1024 + tid * 4;
  *(s16x4*)&hi[ib] = h;
  *(s16x4*)&lo[ib] = l;
}

// ---------- RMSNorm fp32 -> bf16 (MoE expert input) ----------
__global__ __launch_bounds__(256) void rms_k(const float* __restrict__ x,
                                             const float* __restrict__ w,
                                             short* __restrict__ obf) {
  const int row = blockIdx.x, tid = threadIdx.x;
  const float* xr = x + (size_t)row * 1024;
  float4 v = *(const float4*)&xr[tid * 4];
  float ss = v.x * v.x + v.y * v.y + v.z * v.z + v.w * v.w;
#pragma unroll
  for (int off = 32; off; off >>= 1) ss += __shfl_down(ss, off);
  __shared__ float red[4];
  if ((tid & 63) == 0) red[tid >> 6] = ss;
  __syncthreads();
  float rs = rsqrtf((red[0] + red[1] + red[2] + red[3]) * (1.f / 1024.f) + 1e-5f);
  float4 wv = *(const float4*)&w[tid * 4];
  s16x4 ob;
  ob.x = f2bf(v.x * rs * wv.x); ob.y = f2bf(v.y * rs * wv.y);
  ob.z = f2bf(v.z * rs * wv.z); ob.w = f2bf(v.w * rs * wv.w);
  *(s16x4*)&obf[(size_t)row * 1024 + tid * 4] = ob;
}

// ---------- bf16x3 split MFMA GEMM (upstream, fp32-equivalent) ----------
template <int EPI>
__global__ __launch_bounds__(256)
void gemm3_k(const short* __restrict__ Ah, const short* __restrict__ Al,
             const short* __restrict__ Bh, const short* __restrict__ Bl,
             float* __restrict__ C, const float* __restrict__ resid,
             int M, int N, int K) {
  __shared__ short sAh[128 * 32];
  __shared__ short sAl[128 * 32];
  __shared__ short sBh[128 * 32];
  __shared__ short sBl[128 * 32];

  const int tid = threadIdx.x;
  const int bn = blockIdx.x, bm = blockIdx.y;
  const int lane = tid & 63, wv = tid >> 6;
  const int rch = lane >> 2, cch = (lane & 3) << 3;
  const int wr = wv >> 1, wc = wv & 1;
  const int lr = lane & 15, lg = lane >> 4;
  const int c0 = wv * 2, c1 = wv * 2 + 1;

  const int ra0 = bm * 128 + c0 * 16 + rch;
  const int ra1 = bm * 128 + c1 * 16 + rch;
  const int rb0 = bn * 128 + c0 * 16 + rch, rb1 = bn * 128 + c1 * 16 + rch;

  f32x4 acc[4][4];
#pragma unroll
  for (int m = 0; m < 4; m++)
#pragma unroll
    for (int n = 0; n < 4; n++) acc[m][n] = (f32x4){0.f, 0.f, 0.f, 0.f};

  const int nk = K >> 5;
  for (int kt = 0; kt < nk; ++kt) {
    __syncthreads();
    const int colk = (kt << 5) + cch;
    gload_lds16(Ah + (size_t)ra0 * K + colk, &sAh[c0 * 512]);
    gload_lds16(Ah + (size_t)ra1 * K + colk, &sAh[c1 * 512]);
    gload_lds16(Al + (size_t)ra0 * K + colk, &sAl[c0 * 512]);
    gload_lds16(Al + (size_t)ra1 * K + colk, &sAl[c1 * 512]);
    gload_lds16(Bh + (size_t)rb0 * K + colk, &sBh[c0 * 512]);
    gload_lds16(Bh + (size_t)rb1 * K + colk, &sBh[c1 * 512]);
    gload_lds16(Bl + (size_t)rb0 * K + colk, &sBl[c0 * 512]);
    gload_lds16(Bl + (size_t)rb1 * K + colk, &sBl[c1 * 512]);
    __syncthreads();
    bf16x8 ah[4], al[4], bh[4], bl[4];
#pragma unroll
    for (int m = 0; m < 4; m++) {
      const int o = (wr * 64 + m * 16 + lr) * 32 + lg * 8;
      ah[m] = *(const bf16x8*)&sAh[o];
      al[m] = *(const bf16x8*)&sAl[o];
    }
#pragma unroll
    for (int n = 0; n < 4; n++) {
      const int o = (wc * 64 + n * 16 + lr) * 32 + lg * 8;
      bh[n] = *(const bf16x8*)&sBh[o];
      bl[n] = *(const bf16x8*)&sBl[o];
    }
#pragma unroll
    for (int m = 0; m < 4; m++)
#pragma unroll
      for (int n = 0; n < 4; n++) {
        acc[m][n] = __builtin_amdgcn_mfma_f32_16x16x32_bf16(ah[m], bh[n], acc[m][n], 0, 0, 0);
        acc[m][n] = __builtin_amdgcn_mfma_f32_16x16x32_bf16(al[m], bh[n], acc[m][n], 0, 0, 0);
        acc[m][n] = __builtin_amdgcn_mfma_f32_16x16x32_bf16(ah[m], bl[n], acc[m][n], 0, 0, 0);
      }
  }

  const int cbase = bn * 128 + wc * 64;
#pragma unroll
  for (int m = 0; m < 4; m++) {
    const int rl = bm * 128 + wr * 64 + m * 16 + lg * 4;
#pragma unroll
    for (int n = 0; n < 4; n++) {
      f32x4 v = acc[m][n];
      const int col = cbase + n * 16 + lr;
#pragma unroll
      for (int j = 0; j < 4; j++) {
        const size_t idx = (size_t)(rl + j) * N + col;
        if (EPI == 0) C[idx] = v[j];
        else C[idx] = v[j] + resid[idx];
      }
    }
  }
}

// ---------- fp32 register-blocked flash attention (hi/lo out, heavy-first) ----------
__global__ __launch_bounds__(256)
void attn32t_k(const float* __restrict__ Q, int ldq,
               const float* __restrict__ K, int ldk,
               const float* __restrict__ V, int ldv,
               short* __restrict__ Oh, short* __restrict__ Ol, int ldo,
               int Tq, int Tkv, int causal, float scale) {
  __shared__ float sQt[64][68];
  __shared__ float sKP[64][68];
  __shared__ float sV[64][68];

  const int idx = blockIdx.x;
  const int qb = 15 - (idx >> 6);
  const int h = (idx >> 2) & 15;
  const int b = idx & 3;
  const int tid = threadIdx.x;
  const int tx = tid & 15, ty = tid >> 4;
  const int hoff = h * 64;
  const int srow = tid >> 2;
  const int scol = (tid & 3) * 4;

  {
    const float* qp = &Q[(size_t)(b * Tq + qb * 64 + srow) * ldq + hoff + scol];
#pragma unroll
    for (int j = 0; j < 4; j++) {
      float4 v = *(const float4*)&qp[j * 16];
      sQt[scol + j * 16 + 0][srow] = v.x;
      sQt[scol + j * 16 + 1][srow] = v.y;
      sQt[scol + j * 16 + 2][srow] = v.z;
      sQt[scol + j * 16 + 3][srow] = v.w;
    }
  }

  float o[4][4];
  float m_run[4], l_run[4];
#pragma unroll
  for (int i = 0; i < 4; i++) {
    m_run[i] = -1e30f; l_run[i] = 0.f;
#pragma unroll
    for (int j = 0; j < 4; j++) o[i][j] = 0.f;
  }

  const int ntiles = causal ? (qb + 1) : (Tkv >> 6);
  for (int kt = 0; kt < ntiles; ++kt) {
    __syncthreads();
    {
      const float* kp = &K[(size_t)(b * Tkv + kt * 64 + srow) * ldk + hoff + scol];
      const float* vp = &V[(size_t)(b * Tkv + kt * 64 + srow) * ldv + hoff + scol];
#pragma unroll
      for (int j = 0; j < 4; j++) {
        float4 kv = *(const float4*)&kp[j * 16];
        sKP[scol + j * 16 + 0][srow] = kv.x;
        sKP[scol + j * 16 + 1][srow] = kv.y;
        sKP[scol + j * 16 + 2][srow] = kv.z;
        sKP[scol + j * 16 + 3][srow] = kv.w;
        *(float4*)&sV[srow][scol + j * 16] = *(const float4*)&vp[j * 16];
      }
    }
    __syncthreads();

    float s[4][4];
#pragma unroll
    for (int i = 0; i < 4; i++)
#pragma unroll
      for (int j = 0; j < 4; j++) s[i][j] = 0.f;
#pragma unroll 2
    for (int d = 0; d < 64; d++) {
      float4 qv = *(const float4*)&sQt[d][ty * 4];
      float4 kv = *(const float4*)&sKP[d][tx * 4];
      float qa[4] = {qv.x, qv.y, qv.z, qv.w};
      float ka[4] = {kv.x, kv.y, kv.z, kv.w};
#pragma unroll
      for (int i = 0; i < 4; i++)
#pragma unroll
        for (int j = 0; j < 4; j++) s[i][j] += qa[i] * ka[j];
    }

#pragma unroll
    for (int i = 0; i < 4; i++) {
      const int qg = qb * 64 + ty * 4 + i;
      float tmax = -1e30f;
#pragma unroll
      for (int j = 0; j < 4; j++) {
        float xv = s[i][j] * scale;
        if (causal && (kt * 64 + tx * 4 + j) > qg) xv = -1e30f;
        s[i][j] = xv;
        tmax = fmaxf(tmax, xv);
      }
      tmax = fmaxf(tmax, __shfl_xor(tmax, 1));
      tmax = fmaxf(tmax, __shfl_xor(tmax, 2));
      tmax = fmaxf(tmax, __shfl_xor(tmax, 4));
      tmax = fmaxf(tmax, __shfl_xor(tmax, 8));
      const float m_new = fmaxf(m_run[i], tmax);
      const float alpha = __expf(m_run[i] - m_new);
      float tsum = 0.f;
#pragma unroll
      for (int j = 0; j < 4; j++) {
        float e = (s[i][j] <= -1e29f) ? 0.f : __expf(s[i][j] - m_new);
        s[i][j] = e; tsum += e;
      }
      tsum += __shfl_xor(tsum, 1);
      tsum += __shfl_xor(tsum, 2);
      tsum += __shfl_xor(tsum, 4);
      tsum += __shfl_xor(tsum, 8);
      l_run[i] = l_run[i] * alpha + tsum;
      m_run[i] = m_new;
#pragma unroll
      for (int j = 0; j < 4; j++) o[i][j] *= alpha;
    }
    __syncthreads();

#pragma unroll
    for (int i = 0; i < 4; i++) {
      float4 pw; pw.x = s[i][0]; pw.y = s[i][1]; pw.z = s[i][2]; pw.w = s[i][3];
      *(float4*)&sKP[ty * 4 + i][tx * 4] = pw;
    }
    __syncthreads();

#pragma unroll 2
    for (int k4 = 0; k4 < 16; k4++) {
      float4 pv[4];
#pragma unroll
      for (int i = 0; i < 4; i++) pv[i] = *(const float4*)&sKP[ty * 4 + i][k4 * 4];
#pragma unroll
      for (int kk = 0; kk < 4; kk++) {
        float4 vv = *(const float4*)&sV[k4 * 4 + kk][tx * 4];
#pragma unroll
        for (int i = 0; i < 4; i++) {
          const float pk = ((const float*)&pv[i])[kk];
          o[i][0] += pk * vv.x; o[i][1] += pk * vv.y;
          o[i][2] += pk * vv.z; o[i][3] += pk * vv.w;
        }
      }
    }
  }

#pragma unroll
  for (int i = 0; i < 4; i++) {
    const float inv = 1.f / l_run[i];
    const size_t ob = (size_t)(b * Tq + qb * 64 + ty * 4 + i) * ldo + hoff + tx * 4;
    s16x4 hh, ll;
    float v0 = o[i][0] * inv, v1 = o[i][1] * inv, v2 = o[i][2] * inv, v3 = o[i][3] * inv;
    hh.x = f2bf(v0); ll.x = f2bf(v0 - bf2f(hh.x));
    hh.y = f2bf(v1); ll.y = f2bf(v1 - bf2f(hh.y));
    hh.z = f2bf(v2); ll.z = f2bf(v2 - bf2f(hh.z));
    hh.w = f2bf(v3); ll.w = f2bf(v3 - bf2f(hh.w));
    *(s16x4*)&Oh[ob] = hh;
    *(s16x4*)&Ol[ob] = ll;
  }
}

// ---------- bf16 MFMA GEMM (MoE, 9 experts incl. shared) ----------
// MODE 1: A rows gathered via row_map. MODE 2: A rows contiguous from offs[e].
// EPI 1: silu->bf16. EPI 3: fp32 store.
template <int EPI, int MODE>
__global__ __launch_bounds__(256)
void gemm_bt_k(const short* __restrict__ A, const short* __restrict__ B,
               void* C, int M, int N, int K,
               const int* __restrict__ row_map,
               const int* __restrict__ counts,
               const int* __restrict__ offs) {
  __shared__ short sA[128 * 32];
  __shared__ short sB[128 * 32];
  __shared__ int sRow[128];

  const int tid = threadIdx.x;
  const int bn = blockIdx.x, bm = blockIdx.y;
  const int e = blockIdx.z;
  const int cnt = counts[e];
  const int base = offs[e];
  if (bm * 128 >= cnt) return;
  const short* Bp = B + (size_t)e * N * K;

  const int lane = tid & 63, wv = tid >> 6;
  const int rch = lane >> 2, cch = (lane & 3) << 3;
  const int wr = wv >> 1, wc = wv & 1;
  const int lr = lane & 15, lg = lane >> 4;
  const int c0 = wv * 2, c1 = wv * 2 + 1;

  int ra0, ra1;
  if (MODE == 2) {
    int rl0 = bm * 128 + c0 * 16 + rch, rl1 = bm * 128 + c1 * 16 + rch;
    ra0 = base + ((rl0 < cnt) ? rl0 : 0);
    ra1 = base + ((rl1 < cnt) ? rl1 : 0);
  } else {
    if (tid < 128) {
      int r = bm * 128 + tid;
      sRow[tid] = (r < cnt) ? row_map[base + r] : row_map[base];
    }
    __syncthreads();
    ra0 = sRow[c0 * 16 + rch];
    ra1 = sRow[c1 * 16 + rch];
  }
  const int rb0 = bn * 128 + c0 * 16 + rch, rb1 = bn * 128 + c1 * 16 + rch;

  f32x4 acc[4][4];
#pragma unroll
  for (int m = 0; m < 4; m++)
#pragma unroll
    for (int n = 0; n < 4; n++) acc[m][n] = (f32x4){0.f, 0.f, 0.f, 0.f};

  const int nk = K >> 5;
  for (int kt = 0; kt < nk; ++kt) {
    __syncthreads();
    const int colk = (kt << 5) + cch;
    gload_lds16(A + (size_t)ra0 * K + colk, &sA[c0 * 512]);
    gload_lds16(A + (size_t)ra1 * K + colk, &sA[c1 * 512]);
    gload_lds16(Bp + (size_t)rb0 * K + colk, &sB[c0 * 512]);
    gload_lds16(Bp + (size_t)rb1 * K + colk, &sB[c1 * 512]);
    __syncthreads();
    bf16x8 a[4], b[4];
#pragma unroll
    for (int m = 0; m < 4; m++) a[m] = *(const bf16x8*)&sA[(wr * 64 + m * 16 + lr) * 32 + lg * 8];
#pragma unroll
    for (int n = 0; n < 4; n++) b[n] = *(const bf16x8*)&sB[(wc * 64 + n * 16 + lr) * 32 + lg * 8];
#pragma unroll
    for (int m = 0; m < 4; m++)
#pragma unroll
      for (int n = 0; n < 4; n++)
        acc[m][n] = __builtin_amdgcn_mfma_f32_16x16x32_bf16(a[m], b[n], acc[m][n], 0, 0, 0);
  }

  const int cbase = bn * 128 + wc * 64;
#pragma unroll
  for (int m = 0; m < 4; m++) {
    const int rl = wr * 64 + m * 16 + lg * 4;
#pragma unroll
    for (int n = 0; n < 4; n++) {
      f32x4 v = acc[m][n];
      const int col = cbase + n * 16 + lr;
#pragma unroll
      for (int j = 0; j < 4; j++) {
        const int rloc = bm * 128 + rl + j;
        if (rloc >= cnt) continue;
        const size_t idx = (size_t)(base + rloc) * N + col;
        float xv = v[j];
        if (EPI == 1) {
          float s = xv / (1.f + __expf(-xv));
          ((short*)C)[idx] = f2bf(s);
        } else {
          ((float*)C)[idx] = xv;
        }
      }
    }
  }
}

// ---------- MoE gating FP64 ----------
__global__ __launch_bounds__(256) void gate_k(const float* __restrict__ H,
                                              const float* __restrict__ w3,
                                              const float* __restrict__ gw,
                                              int* counts, int* tok_e, int* tok_s,
                                              float* tok_g) {
  const int token = blockIdx.x * 4 + (threadIdx.x >> 6);
  const int lane = threadIdx.x & 63;
  const float* xr = H + (size_t)token * 1024;
  double a[8] = {0, 0, 0, 0, 0, 0, 0, 0};
  double ss = 0.0;
#pragma unroll
  for (int i = 0; i < 4; i++) {
    float4 xv = *(const float4*)&xr[i * 256 + lane * 4];
    float4 w3v = *(const float4*)&w3[i * 256 + lane * 4];
    ss += (double)xv.x * xv.x + (double)xv.y * xv.y + (double)xv.z * xv.z + (double)xv.w * xv.w;
    double xw0 = (double)xv.x * (double)w3v.x, xw1 = (double)xv.y * (double)w3v.y;
    double xw2 = (double)xv.z * (double)w3v.z, xw3 = (double)xv.w * (double)w3v.w;
#pragma unroll
    for (int e = 0; e < 8; e++) {
      float4 wv = *(const float4*)&gw[e * 1024 + i * 256 + lane * 4];
      a[e] += xw0 * wv.x + xw1 * wv.y + xw2 * wv.z + xw3 * wv.w;
    }
  }
#pragma unroll
  for (int off = 32; off; off >>= 1) {
    ss += __shfl_down(ss, off);
#pragma unroll
    for (int e = 0; e < 8; e++) a[e] += __shfl_down(a[e], off);
  }
  if (lane == 0) {
    double v0 = a[0]; int i0 = 0;
#pragma unroll
    for (int e = 1; e < 8; e++) if (a[e] > v0) { v0 = a[e]; i0 = e; }
    double v1 = -1e300; int i1 = 0;
#pragma unroll
    for (int e = 0; e < 8; e++) if (e != i0 && a[e] > v1) { v1 = a[e]; i1 = e; }
    double rs = 1.0 / sqrt(ss * (1.0 / 1024.0) + 1e-5);
    double t = exp((v1 - v0) * rs);
    double g0 = 1.0 / (1.0 + t);
    int s0 = atomicAdd(&counts[i0], 1);
    int s1 = atomicAdd(&counts[i1], 1);
    tok_e[2 * token] = i0; tok_e[2 * token + 1] = i1;
    tok_s[2 * token] = s0; tok_s[2 * token + 1] = s1;
    tok_g[2 * token] = (float)g0; tok_g[2 * token + 1] = (float)(1.0 - g0);
  }
}

__global__ void offsets_k(int* counts, int* offs) {
  if (threadIdx.x == 0 && blockIdx.x == 0) {
    counts[8] = 4096;  // shared expert: all tokens
    int s = 0;
    for (int e = 0; e < 9; e++) { offs[e] = s; s += counts[e]; }
  }
}

__global__ __launch_bounds__(256) void build_rows_k(const int* __restrict__ offs,
                                                    const int* __restrict__ tok_e,
                                                    const int* __restrict__ tok_s,
                                                    int* __restrict__ row_map,
                                                    int* __restrict__ tok_row) {
  int n = blockIdx.x * 256 + threadIdx.x;
  int e0 = tok_e[2 * n], e1 = tok_e[2 * n + 1];
  int r0 = offs[e0] + tok_s[2 * n], r1 = offs[e1] + tok_s[2 * n + 1];
  row_map[r0] = n; row_map[r1] = n;
  row_map[8192 + n] = n;  // shared expert identity rows
  tok_row[2 * n] = r0; tok_row[2 * n + 1] = r1;
}

// ---------- final combine: out = H + eo_shared + g0*eo0 + g1*eo1 ----------
__global__ __launch_bounds__(256) void combine_k(const float* __restrict__ H,
                                                 const float* __restrict__ eo,
                                                 const int* __restrict__ tok_row,
                                                 const float* __restrict__ tok_g,
                                                 float* __restrict__ out) {
  const int n = blockIdx.x, t = threadIdx.x;
  const int r0 = tok_row[2 * n], r1 = tok_row[2 * n + 1];
  const float g0 = tok_g[2 * n], g1 = tok_g[2 * n + 1];
  const size_t ib = (size_t)n * 1024 + t * 4;
  float4 hv = *(const float4*)&H[ib];
  float4 sv = *(const float4*)&eo[(size_t)(8192 + n) * 1024 + t * 4];
  float4 a0 = *(const float4*)&eo[(size_t)r0 * 1024 + t * 4];
  float4 a1 = *(const float4*)&eo[(size_t)r1 * 1024 + t * 4];
  float4 ov;
  ov.x = hv.x + sv.x + g0 * a0.x + g1 * a1.x;
  ov.y = hv.y + sv.y + g0 * a0.y + g1 * a1.y;
  ov.z = hv.z + sv.z + g0 * a0.z + g1 * a1.z;
  ov.w = hv.w + sv.w + g0 * a0.w + g1 * a1.w;
  *(float4*)&out[ib] = ov;
}

// ---------- host ----------
extern "C" void kernel_launch(void* const* d_in, const int* in_sizes, int n_in,
                              void* d_out, int out_size, void* d_ws, size_t ws_size,
                              hipStream_t stream) {
  (void)in_sizes; (void)n_in; (void)out_size;
  const float* x     = (const float*)d_in[0];
  const float* enc   = (const float*)d_in[1];
  const float* n1w   = (const float*)d_in[4];
  const float* n2w   = (const float*)d_in[5];
  const float* n3w   = (const float*)d_in[6];
  const float* sa_wq = (const float*)d_in[7];
  const float* sa_wk = (const float*)d_in[8];
  const float* sa_wv = (const float*)d_in[9];
  const float* sa_wo = (const float*)d_in[10];
  const float* ca_wq = (const float*)d_in[11];
  const float* ca_wk = (const float*)d_in[12];
  const float* ca_wv = (const float*)d_in[13];
  const float* ca_wo = (const float*)d_in[14];
  const float* gw    = (const float*)d_in[15];
  const float* e_w1  = (const float*)d_in[16];
  const float* e_w2  = (const float*)d_in[17];
  const float* s_w1  = (const float*)d_in[18];
  const float* s_w2  = (const float*)d_in[19];
  float* out = (float*)d_out;

  char* p = (char*)d_ws;
  size_t off = 0;
  auto alloc = [&](size_t bytes) -> void* {
    void* r = p + off;
    off += (bytes + 255) & ~(size_t)255;
    return r;
  };
  // 9-expert MoE weights (expert 8 = shared)
  short* w_all1 = (short*)alloc(9LL * 4096 * 1024 * 2);
  short* w_all2 = (short*)alloc(9LL * 1024 * 4096 * 2);
  short* xn     = (short*)alloc(4096LL * 1024 * 2);
  // union region: qkvb (48 MB, attention) / hbuf (96 MB, MoE hidden)
  char*  U      = (char*)alloc(12288LL * 4096 * 2);
  float* qkvb   = (float*)U;
  short* hbuf   = (short*)U;
  float* Hb     = (float*)alloc(4096LL * 1024 * 4);
  float* eo     = (float*)alloc(12288LL * 1024 * 4);
  short* xh     = (short*)alloc(4096LL * 1024 * 2);
  short* xl     = (short*)alloc(4096LL * 1024 * 2);
  short* ench   = (short*)alloc(256LL * 1024 * 2);
  short* encl   = (short*)alloc(256LL * 1024 * 2);
  short* wsh    = (short*)alloc(3072LL * 1024 * 2);
  short* wsl    = (short*)alloc(3072LL * 1024 * 2);
  int*   counts = (int*)alloc(9 * 4);
  int*   offs   = (int*)alloc(9 * 4);
  int*   tok_e  = (int*)alloc(4096LL * 2 * 4);
  int*   tok_s  = (int*)alloc(4096LL * 2 * 4);
  float* tok_g  = (float*)alloc(4096LL * 2 * 4);
  int*   tok_row= (int*)alloc(4096LL * 2 * 4);
  int*   row_map= (int*)alloc(12288LL * 4);
  if (off > ws_size) return;

  float* crossQ = qkvb;                    // [4096][1024]
  float* encKV  = qkvb + 8388608;          // [256][2048]

  auto cvt = [&](const float* s, short* d, long n) {
    long n4 = n / 4;
    long g = (n4 + 255) / 256;
    int grid = (int)(g > 4096 ? 4096 : g);
    cvt_k<<<grid, 256, 0, stream>>>(s, d, n4);
  };
  auto cvt2 = [&](const float* s, short* h, short* l, long n) {
    long n4 = n / 4;
    long g = (n4 + 255) / 256;
    int grid = (int)(g > 4096 ? 4096 : g);
    cvt2_k<<<grid, 256, 0, stream>>>(s, h, l, n4);
  };

  // MoE weights -> bf16, 9-expert layout
  cvt(e_w1, w_all1, 8L * 4096 * 1024);
  cvt(s_w1, w_all1 + 8L * 4096 * 1024, 4096L * 1024);
  cvt(e_w2, w_all2, 8L * 1024 * 4096);
  cvt(s_w2, w_all2 + 8L * 1024 * 4096, 1024L * 4096);
  cvt2(enc, ench, encl, 256L * 1024);

  // ---- self attention ----
  rms2_k<<<4096, 256, 0, stream>>>(x, n1w, xh, xl);
  cvt2(sa_wq, wsh, wsl, 1024L * 1024);
  cvt2(sa_wk, wsh + 1048576, wsl + 1048576, 1024L * 1024);
  cvt2(sa_wv, wsh + 2097152, wsl + 2097152, 1024L * 1024);
  gemm3_k<0><<<dim3(24, 32), 256, 0, stream>>>(xh, xl, wsh, wsl, qkvb, nullptr,
      4096, 3072, 1024);
  attn32t_k<<<1024, 256, 0, stream>>>(qkvb, 3072, qkvb + 1024, 3072, qkvb + 2048, 3072,
      xh, xl, 1024, 1024, 1024, 1, 0.125f);
  cvt2(sa_wo, wsh, wsl, 1024L * 1024);
  gemm3_k<2><<<dim3(8, 32), 256, 0, stream>>>(xh, xl, wsh, wsl, Hb, x,
      4096, 1024, 1024);

  // ---- cross attention ----
  rms2_k<<<4096, 256, 0, stream>>>(Hb, n2w, xh, xl);
  cvt2(ca_wq, wsh, wsl, 1024L * 1024);
  gemm3_k<0><<<dim3(8, 32), 256, 0, stream>>>(xh, xl, wsh, wsl, crossQ, nullptr,
      4096, 1024, 1024);
  cvt2(ca_wk, wsh, wsl, 1024L * 1024);
  cvt2(ca_wv, wsh + 1048576, wsl + 1048576, 1024L * 1024);
  gemm3_k<0><<<dim3(16, 2), 256, 0, stream>>>(ench, encl, wsh, wsl, encKV, nullptr,
      256, 2048, 1024);
  attn32t_k<<<1024, 256, 0, stream>>>(crossQ, 1024, encKV, 2048, encKV + 1024, 2048,
      xh, xl, 1024, 1024, 64, 0, 0.125f);
  cvt2(ca_wo, wsh, wsl, 1024L * 1024);
  gemm3_k<2><<<dim3(8, 32), 256, 0, stream>>>(xh, xl, wsh, wsl, Hb, Hb,
      4096, 1024, 1024);

  // ---- MoE: fp64 gate; 9-expert bf16 MFMA (routed top-2 + shared) ----
  rms_k<<<4096, 256, 0, stream>>>(Hb, n3w, xn);
  hipMemsetAsync(counts, 0, 8 * sizeof(int), stream);
  gate_k<<<1024, 256, 0, stream>>>(Hb, n3w, gw, counts, tok_e, tok_s, tok_g);
  offsets_k<<<1, 1, 0, stream>>>(counts, offs);
  build_rows_k<<<16, 256, 0, stream>>>(offs, tok_e, tok_s, row_map, tok_row);
  // w1 (gathered rows, 9 experts) + silu -> hbuf (bf16)
  gemm_bt_k<1, 1><<<dim3(32, 32, 9), 256, 0, stream>>>(xn, w_all1, hbuf,
      4096, 4096, 1024, row_map, counts, offs);
  // w2 (contiguous rows, 9 experts) -> eo (fp32)
  gemm_bt_k<3, 2><<<dim3(8, 32, 9), 256, 0, stream>>>(hbuf, w_all2, eo,
      4096, 1024, 4096, nullptr, counts, offs);

  combine_k<<<4096, 256, 0, stream>>>(Hb, eo, tok_row, tok_g, out);
}